// Round 6
// baseline (17418.932 us; speedup 1.0000x reference)
//
#include <hip/hip_runtime.h>
#include <hip/hip_bf16.h>

#define B 128
#define P 196
#define PP 200       // padded P (bf16 rows 400B, 16B-aligned)
#define ENC 512
#define DEC 512
#define ATT 256
#define EMB 256
#define V 5000
#define S 256
#define S1 257
#define NG 2048      // 4*DEC
#define KS 8         // k-splits for gates GEMM

typedef __attribute__((ext_vector_type(4))) short s4v;
typedef __attribute__((ext_vector_type(8))) short s8v;

__device__ __forceinline__ float bf2f(short u) {
    unsigned int x = ((unsigned int)(unsigned short)u) << 16;
    float f; __builtin_memcpy(&f, &x, 4); return f;
}

// ---------------- mean over P ----------------
__global__ __launch_bounds__(256) void k_mean(const float* __restrict__ feat,
                                              float* __restrict__ mean_f) {
    int idx = blockIdx.x * 256 + threadIdx.x;
    int b = idx >> 9, e = idx & 511;
    const float* fp = feat + (size_t)b * P * ENC + e;
    float s = 0.f;
    for (int p = 0; p < P; ++p) s += fp[(size_t)p * ENC];
    mean_f[idx] = s * (1.0f / (float)P);
}

// ---------------- h0 / c0 ----------------
__global__ __launch_bounds__(256) void k_init_hc(const float* __restrict__ mean_f,
        const float* __restrict__ ih_w, const float* __restrict__ ih_b,
        const float* __restrict__ ic_w, const float* __restrict__ ic_b,
        float* __restrict__ h, float* __restrict__ c) {
    int idx = blockIdx.x * 256 + threadIdx.x;
    int b = idx >> 9, d = idx & 511;
    const float* mf = mean_f + (size_t)b * ENC;
    float sh = ih_b[d], sc = ic_b[d];
    for (int e = 0; e < ENC; ++e) {
        float m = mf[e];
        sh = fmaf(m, ih_w[(size_t)e * DEC + d], sh);
        sc = fmaf(m, ic_w[(size_t)e * DEC + d], sc);
    }
    h[idx] = sh; c[idx] = sc;
}

// ---------------- Uf = features @ Ua_w + Ua_b  (bf16 out) ----------------
__global__ __launch_bounds__(256) void k_uf(const float* __restrict__ feat,
        const float* __restrict__ Ua_w, const float* __restrict__ Ua_b,
        __hip_bfloat16* __restrict__ Uf) {
    int row0 = blockIdx.x * 8;
    int a = threadIdx.x;
    __shared__ float fs[8][ENC];
    for (int i = threadIdx.x; i < 8 * ENC; i += 256) {
        int r = i >> 9, e = i & 511;
        fs[r][e] = feat[(size_t)(row0 + r) * ENC + e];
    }
    __syncthreads();
    float acc[8];
    float bia = Ua_b[a];
#pragma unroll
    for (int r = 0; r < 8; ++r) acc[r] = bia;
    for (int e = 0; e < ENC; ++e) {
        float w = Ua_w[(size_t)e * ATT + a];
#pragma unroll
        for (int r = 0; r < 8; ++r) acc[r] = fmaf(fs[r][e], w, acc[r]);
    }
#pragma unroll
    for (int r = 0; r < 8; ++r)
        Uf[(size_t)(row0 + r) * ATT + a] = __float2bfloat16(acc[r]);
}

// ---------------- featT[b][e][p] bf16, zero-padded to PP ----------------
__global__ __launch_bounds__(512) void k_featT(const float* __restrict__ feat,
        __hip_bfloat16* __restrict__ featT) {
    int b = blockIdx.x, p0 = blockIdx.y * 8;
    int e = threadIdx.x;
    __hip_bfloat16 v[8];
#pragma unroll
    for (int i = 0; i < 8; ++i) {
        int p = p0 + i;
        float f = (p < P) ? feat[((size_t)b * P + p) * ENC + e] : 0.f;
        v[i] = __float2bfloat16(f);
    }
    __builtin_memcpy(&featT[((size_t)b * ENC + e) * PP + p0], v, 16);
}

// ---------------- Wa_w -> bf16 ----------------
__global__ __launch_bounds__(256) void k_wacvt(const float* __restrict__ w,
        __hip_bfloat16* __restrict__ wb) {
    int i = blockIdx.x * 256 + threadIdx.x;   // DEC*ATT = 131072
    wb[i] = __float2bfloat16(w[i]);
}

// ---------------- Gemb = embeds[:, :S] @ W_ih[:EMB]  (bf16 out) ----------------
__global__ __launch_bounds__(256) void k_gemb(const float* __restrict__ emb,
        const int* __restrict__ captions, const float* __restrict__ W_ih,
        __hip_bfloat16* __restrict__ Gemb) {
    __shared__ float As[16][128];
    __shared__ float Bs[16][128];
    __shared__ int rowcap[128];
    int m0 = blockIdx.x * 128;
    int n0 = blockIdx.y * 128;
    int tid = threadIdx.x;
    if (tid < 128) {
        int m = m0 + tid;
        rowcap[tid] = captions[(size_t)(m & 127) * S1 + (m >> 7)];
    }
    __syncthreads();
    int tx = tid & 15, ty = tid >> 4;
    float acc[8][8];
#pragma unroll
    for (int i = 0; i < 8; ++i)
#pragma unroll
        for (int j = 0; j < 8; ++j) acc[i][j] = 0.f;
    int arow = tid >> 1, ak = (tid & 1) * 8;
    int bkk = tid >> 4, bn = (tid & 15) * 8;
    for (int k0 = 0; k0 < EMB; k0 += 16) {
        {
            const float* ap = emb + (size_t)rowcap[arow] * EMB + k0 + ak;
            float4 v0 = *(const float4*)ap;
            float4 v1 = *(const float4*)(ap + 4);
            As[ak + 0][arow] = v0.x; As[ak + 1][arow] = v0.y;
            As[ak + 2][arow] = v0.z; As[ak + 3][arow] = v0.w;
            As[ak + 4][arow] = v1.x; As[ak + 5][arow] = v1.y;
            As[ak + 6][arow] = v1.z; As[ak + 7][arow] = v1.w;
        }
        {
            const float* bp = W_ih + (size_t)(k0 + bkk) * NG + n0 + bn;
            *(float4*)&Bs[bkk][bn] = *(const float4*)bp;
            *(float4*)&Bs[bkk][bn + 4] = *(const float4*)(bp + 4);
        }
        __syncthreads();
#pragma unroll
        for (int kk = 0; kk < 16; ++kk) {
            float4 a0 = *(const float4*)&As[kk][ty * 8];
            float4 a1 = *(const float4*)&As[kk][ty * 8 + 4];
            float4 b0 = *(const float4*)&Bs[kk][tx * 8];
            float4 b1 = *(const float4*)&Bs[kk][tx * 8 + 4];
            float av[8] = {a0.x, a0.y, a0.z, a0.w, a1.x, a1.y, a1.z, a1.w};
            float bv[8] = {b0.x, b0.y, b0.z, b0.w, b1.x, b1.y, b1.z, b1.w};
#pragma unroll
            for (int i = 0; i < 8; ++i)
#pragma unroll
                for (int j = 0; j < 8; ++j)
                    acc[i][j] = fmaf(av[i], bv[j], acc[i][j]);
        }
        __syncthreads();
    }
#pragma unroll
    for (int i = 0; i < 8; ++i) {
        __hip_bfloat16* gp = Gemb + (size_t)(m0 + ty * 8 + i) * NG + n0 + tx * 8;
#pragma unroll
        for (int j = 0; j < 8; ++j) gp[j] = __float2bfloat16(acc[i][j]);
    }
}

// ======== fused: cell (reduce partials) + wah + half-attention ========
// 256 blocks (b, half) x 512 threads. Both halves redo the cell (cheap,
// keeps h block-local); only half 0 writes h/c/Hall. c is ping-pong
// buffered (cr read, cw write) to avoid the cross-block race.
// t==0: no cell (h from hbuf). t==S: cell only.
__global__ __launch_bounds__(512) void k_attn_cell(
        const float* __restrict__ partials, const __hip_bfloat16* __restrict__ Gemb,
        const float* __restrict__ b_ih, const float* __restrict__ b_hh,
        float* __restrict__ h, const float* __restrict__ cr, float* __restrict__ cw,
        float* __restrict__ Hall,
        const __hip_bfloat16* __restrict__ Wa_wb, const float* __restrict__ Wa_b,
        const __hip_bfloat16* __restrict__ Uf, const __hip_bfloat16* __restrict__ featT,
        const float* __restrict__ va_w, const float* __restrict__ va_b,
        float* __restrict__ ctxp, float* __restrict__ mlp,
        int t, int use_gemb, int use_hall) {
    int g = blockIdx.x;
    int b = g >> 1, half = g & 1;
    int tid = threadIdx.x;
    int base = half ? 96 : 0;
    int cnt  = half ? 100 : 96;    // real positions
    int nchunk = half ? 13 : 12;   // 8-wide chunks (incl. pads)
    __shared__ float hs[DEC];
    __shared__ float wahp[2][ATT];
    __shared__ float wahs[ATT];
    __shared__ float sc[104];
    __shared__ float red[4];

    // ---- cell ----
    if (t > 0) {
        int d = tid;
        float s0 = b_ih[d]           + b_hh[d];
        float s1 = b_ih[d + DEC]     + b_hh[d + DEC];
        float s2 = b_ih[d + 2 * DEC] + b_hh[d + 2 * DEC];
        float s3 = b_ih[d + 3 * DEC] + b_hh[d + 3 * DEC];
#pragma unroll
        for (int ks = 0; ks < KS; ++ks) {
            const float* pp = partials + ((size_t)ks * B + b) * NG + d;
            s0 += pp[0]; s1 += pp[DEC]; s2 += pp[2 * DEC]; s3 += pp[3 * DEC];
        }
        if (use_gemb) {
            const __hip_bfloat16* gp = Gemb + ((size_t)(t - 1) * B + b) * NG + d;
            s0 += __bfloat162float(gp[0]);
            s1 += __bfloat162float(gp[DEC]);
            s2 += __bfloat162float(gp[2 * DEC]);
            s3 += __bfloat162float(gp[3 * DEC]);
        }
        size_t gidx = (size_t)b * DEC + d;
        float ii = 1.f / (1.f + __expf(-s0));
        float ff = 1.f / (1.f + __expf(-s1));
        float gg = tanhf(s2);
        float oo = 1.f / (1.f + __expf(-s3));
        float cn = ff * cr[gidx] + ii * gg;
        float hn = oo * tanhf(cn);
        hs[d] = hn;
        if (half == 0) {
            cw[gidx] = cn;
            h[gidx] = hn;
            if (use_hall) Hall[((size_t)(t - 1) * B + b) * DEC + d] = hn;
        }
    } else {
        hs[tid] = h[(size_t)b * DEC + tid];
    }
    __syncthreads();
    if (t == S) return;

    // ---- wah GEMV: thread (a, q) covers d in [q*256, q*256+256) ----
    {
        int a = tid & 255, q = tid >> 8;
        float acc = 0.f;
        const __hip_bfloat16* wp = Wa_wb + (size_t)(q * 256) * ATT + a;
        const float* hq = &hs[q * 256];
#pragma unroll 4
        for (int dd = 0; dd < 256; ++dd)
            acc = fmaf(hq[dd], bf2f(*(const short*)&wp[(size_t)dd * ATT]), acc);
        wahp[q][a] = acc;
    }
    __syncthreads();
    if (tid < ATT) wahs[tid] = Wa_b[tid] + wahp[0][tid] + wahp[1][tid];
    __syncthreads();

    // ---- scores: 8 waves, local pl stride-8; lane covers 4 a's ----
    {
        int w = tid >> 6, lane = tid & 63;
        float4 wv = *(const float4*)&wahs[lane * 4];
        float4 vv = *(const float4*)&va_w[lane * 4];
        float vb = va_b[0];
        for (int pl = w; pl < cnt; pl += 8) {
            const __hip_bfloat16* ufp = Uf + ((size_t)b * P + base + pl) * ATT + lane * 4;
            s4v u4 = *(const s4v*)ufp;
            float ssc = vv.x * tanhf(bf2f(u4.x) + wv.x) + vv.y * tanhf(bf2f(u4.y) + wv.y)
                      + vv.z * tanhf(bf2f(u4.z) + wv.z) + vv.w * tanhf(bf2f(u4.w) + wv.w);
#pragma unroll
            for (int off = 32; off; off >>= 1) ssc += __shfl_down(ssc, off);
            if (lane == 0) sc[pl] = ssc + vb;
        }
    }
    __syncthreads();

    // ---- local softmax over cnt ----
    {
        int lane = tid & 63;
        float v = (tid < cnt) ? sc[tid] : -1e30f;
        if (tid < 128) {
            float m = v;
#pragma unroll
            for (int off = 32; off; off >>= 1) m = fmaxf(m, __shfl_down(m, off));
            if (lane == 0) red[tid >> 6] = m;
        }
        __syncthreads();
        float mh = fmaxf(red[0], red[1]);
        float e = (tid < cnt) ? __expf(v - mh) : 0.f;
        if (tid < 128) {
            float l = e;
#pragma unroll
            for (int off = 32; off; off >>= 1) l += __shfl_down(l, off);
            if (lane == 0) red[2 + (tid >> 6)] = l;
        }
        __syncthreads();
        if (tid < cnt) sc[tid] = e;
        else if (tid < 104) sc[tid] = 0.f;
        if (tid == 0) {
            mlp[((size_t)half * B + b) * 2 + 0] = mh;
            mlp[((size_t)half * B + b) * 2 + 1] = red[2] + red[3];
        }
    }
    __syncthreads();

    // ---- partial (unnormalized) context ----
    {
        float acc = 0.f;
        const __hip_bfloat16* fr = featT + ((size_t)b * ENC + tid) * PP + base;
        for (int ch = 0; ch < nchunk; ++ch) {
            s8v raw = *(const s8v*)(fr + ch * 8);
            const float* sp = &sc[ch * 8];
#pragma unroll
            for (int j = 0; j < 8; ++j)
                acc = fmaf(sp[j], bf2f(raw[j]), acc);
        }
        ctxp[((size_t)half * B + b) * ENC + tid] = acc;
    }
}

// ---------------- gates partial GEMM with inline ctx combine ----------------
__global__ __launch_bounds__(256) void k_gates(const float* __restrict__ emb,
        const int* __restrict__ captions, int t,
        const float* __restrict__ ctxp, const float* __restrict__ mlp,
        const float* __restrict__ h,
        const float* __restrict__ W_ih, const float* __restrict__ W_hh,
        float* __restrict__ partials, int use_gemb) {
    __shared__ float As[16][128];
    __shared__ float Bs[16][64];
    __shared__ float sw0[B], sw1[B];
    __shared__ int scap[B];
    int n0 = blockIdx.x * 64;
    int ks = blockIdx.y;
    int tid = threadIdx.x;
    int kch = use_gemb ? 128 : 160;
    if (tid < B) {
        float m0 = mlp[(size_t)tid * 2 + 0];
        float l0 = mlp[(size_t)tid * 2 + 1];
        float m1 = mlp[((size_t)B + tid) * 2 + 0];
        float l1 = mlp[((size_t)B + tid) * 2 + 1];
        float M = fmaxf(m0, m1);
        float e0 = __expf(m0 - M), e1 = __expf(m1 - M);
        float inv = 1.f / (l0 * e0 + l1 * e1);
        sw0[tid] = e0 * inv; sw1[tid] = e1 * inv;
        if (!use_gemb) scap[tid] = captions[(size_t)tid * S1 + t];
    }
    __syncthreads();
    int tx = tid & 15, ty = tid >> 4;
    float acc[8][4];
#pragma unroll
    for (int i = 0; i < 8; ++i)
#pragma unroll
        for (int j = 0; j < 4; ++j) acc[i][j] = 0.f;
    int arow = tid >> 1, ak = (tid & 1) * 8;
    int bkk = tid >> 4, bn = (tid & 15) * 4;
    for (int k0 = ks * kch; k0 < ks * kch + kch; k0 += 16) {
        {
            int k = k0 + ak;
            if (!use_gemb && k < EMB) {
                const float* ap = emb + (size_t)scap[arow] * EMB + k;
                float4 v0 = *(const float4*)ap;
                float4 v1 = *(const float4*)(ap + 4);
                As[ak + 0][arow] = v0.x; As[ak + 1][arow] = v0.y;
                As[ak + 2][arow] = v0.z; As[ak + 3][arow] = v0.w;
                As[ak + 4][arow] = v1.x; As[ak + 5][arow] = v1.y;
                As[ak + 6][arow] = v1.z; As[ak + 7][arow] = v1.w;
            } else {
                int kc = use_gemb ? k : (k - EMB);
                if (kc < ENC) {
                    const float* p0 = ctxp + (size_t)arow * ENC + kc;
                    const float* p1 = ctxp + ((size_t)B + arow) * ENC + kc;
                    float w0 = sw0[arow], w1 = sw1[arow];
                    float4 a0 = *(const float4*)p0;
                    float4 a1 = *(const float4*)(p0 + 4);
                    float4 b0 = *(const float4*)p1;
                    float4 b1 = *(const float4*)(p1 + 4);
                    As[ak + 0][arow] = a0.x * w0 + b0.x * w1;
                    As[ak + 1][arow] = a0.y * w0 + b0.y * w1;
                    As[ak + 2][arow] = a0.z * w0 + b0.z * w1;
                    As[ak + 3][arow] = a0.w * w0 + b0.w * w1;
                    As[ak + 4][arow] = a1.x * w0 + b1.x * w1;
                    As[ak + 5][arow] = a1.y * w0 + b1.y * w1;
                    As[ak + 6][arow] = a1.z * w0 + b1.z * w1;
                    As[ak + 7][arow] = a1.w * w0 + b1.w * w1;
                } else {
                    const float* ap = h + (size_t)arow * DEC + (kc - ENC);
                    float4 v0 = *(const float4*)ap;
                    float4 v1 = *(const float4*)(ap + 4);
                    As[ak + 0][arow] = v0.x; As[ak + 1][arow] = v0.y;
                    As[ak + 2][arow] = v0.z; As[ak + 3][arow] = v0.w;
                    As[ak + 4][arow] = v1.x; As[ak + 5][arow] = v1.y;
                    As[ak + 6][arow] = v1.z; As[ak + 7][arow] = v1.w;
                }
            }
        }
        {
            int k = k0 + bkk;
            const float* bp;
            if (use_gemb)
                bp = (k < ENC) ? W_ih + (size_t)(k + EMB) * NG + n0 + bn
                               : W_hh + (size_t)(k - ENC) * NG + n0 + bn;
            else
                bp = (k < EMB + ENC) ? W_ih + (size_t)k * NG + n0 + bn
                                     : W_hh + (size_t)(k - EMB - ENC) * NG + n0 + bn;
            *(float4*)&Bs[bkk][bn] = *(const float4*)bp;
        }
        __syncthreads();
#pragma unroll
        for (int kk = 0; kk < 16; ++kk) {
            float4 a0 = *(const float4*)&As[kk][ty * 8];
            float4 a1 = *(const float4*)&As[kk][ty * 8 + 4];
            float4 b0 = *(const float4*)&Bs[kk][tx * 4];
            float av[8] = {a0.x, a0.y, a0.z, a0.w, a1.x, a1.y, a1.z, a1.w};
            float bv[4] = {b0.x, b0.y, b0.z, b0.w};
#pragma unroll
            for (int i = 0; i < 8; ++i)
#pragma unroll
                for (int j = 0; j < 4; ++j)
                    acc[i][j] = fmaf(av[i], bv[j], acc[i][j]);
        }
        __syncthreads();
    }
#pragma unroll
    for (int i = 0; i < 8; ++i) {
        int mrow = ty * 8 + i;
        float* pp = partials + ((size_t)ks * B + mrow) * NG + n0 + tx * 4;
        *(float4*)pp = make_float4(acc[i][0], acc[i][1], acc[i][2], acc[i][3]);
    }
}

// ---------------- output projection GEMM ----------------
__global__ __launch_bounds__(256) void k_fcn(const float* __restrict__ A,
        const float* __restrict__ Bw, const float* __restrict__ bias,
        float* __restrict__ out, int t_fix) {
    __shared__ float As[16][128];
    __shared__ float Bs[16][128];
    int m0 = blockIdx.x * 128;
    int n0 = blockIdx.y * 128;
    int tid = threadIdx.x;
    int tx = tid & 15, ty = tid >> 4;
    float acc[8][8];
#pragma unroll
    for (int i = 0; i < 8; ++i)
#pragma unroll
        for (int j = 0; j < 8; ++j) acc[i][j] = 0.f;
    int arow = tid >> 1, ak = (tid & 1) * 8;
    int bkk = tid >> 4, bn = (tid & 15) * 8;
    const float4 z4 = make_float4(0.f, 0.f, 0.f, 0.f);
    for (int k0 = 0; k0 < DEC; k0 += 16) {
        {
            const float* ap = A + (size_t)(m0 + arow) * DEC + k0 + ak;
            float4 v0 = *(const float4*)ap;
            float4 v1 = *(const float4*)(ap + 4);
            As[ak + 0][arow] = v0.x; As[ak + 1][arow] = v0.y;
            As[ak + 2][arow] = v0.z; As[ak + 3][arow] = v0.w;
            As[ak + 4][arow] = v1.x; As[ak + 5][arow] = v1.y;
            As[ak + 6][arow] = v1.z; As[ak + 7][arow] = v1.w;
        }
        {
            int n4 = n0 + bn;
            const float* bp = Bw + (size_t)(k0 + bkk) * V + n4;
            float4 v0 = (n4 < V) ? *(const float4*)bp : z4;
            float4 v1 = (n4 + 4 < V) ? *(const float4*)(bp + 4) : z4;
            *(float4*)&Bs[bkk][bn] = v0;
            *(float4*)&Bs[bkk][bn + 4] = v1;
        }
        __syncthreads();
#pragma unroll
        for (int kk = 0; kk < 16; ++kk) {
            float4 a0 = *(const float4*)&As[kk][ty * 8];
            float4 a1 = *(const float4*)&As[kk][ty * 8 + 4];
            float4 b0 = *(const float4*)&Bs[kk][tx * 8];
            float4 b1 = *(const float4*)&Bs[kk][tx * 8 + 4];
            float av[8] = {a0.x, a0.y, a0.z, a0.w, a1.x, a1.y, a1.z, a1.w};
            float bv[8] = {b0.x, b0.y, b0.z, b0.w, b1.x, b1.y, b1.z, b1.w};
#pragma unroll
            for (int i = 0; i < 8; ++i)
#pragma unroll
                for (int j = 0; j < 8; ++j)
                    acc[i][j] = fmaf(av[i], bv[j], acc[i][j]);
        }
        __syncthreads();
    }
#pragma unroll
    for (int i = 0; i < 8; ++i) {
        int mrow = m0 + ty * 8 + i;
        int bb, tt;
        if (t_fix >= 0) { bb = mrow; tt = t_fix; }
        else            { tt = mrow >> 7; bb = mrow & 127; }
        float* op = out + ((size_t)bb * S + tt) * V + n0 + tx * 8;
#pragma unroll
        for (int j = 0; j < 8; ++j) {
            int n = n0 + tx * 8 + j;
            if (n < V) op[j] = acc[i][j] + bias[n];
        }
    }
}

extern "C" void kernel_launch(void* const* d_in, const int* in_sizes, int n_in,
                              void* d_out, int out_size, void* d_ws, size_t ws_size,
                              hipStream_t stream) {
    const float* features = (const float*)d_in[0];
    const int*   captions = (const int*)d_in[1];
    const float* emb      = (const float*)d_in[2];
    const float* Ua_w     = (const float*)d_in[3];
    const float* Ua_b     = (const float*)d_in[4];
    const float* Wa_w     = (const float*)d_in[5];
    const float* Wa_b     = (const float*)d_in[6];
    const float* va_w     = (const float*)d_in[7];
    const float* va_b     = (const float*)d_in[8];
    const float* ih_w     = (const float*)d_in[9];
    const float* ih_b     = (const float*)d_in[10];
    const float* ic_w     = (const float*)d_in[11];
    const float* ic_b     = (const float*)d_in[12];
    const float* W_ih     = (const float*)d_in[13];
    const float* b_ih     = (const float*)d_in[14];
    const float* W_hh     = (const float*)d_in[15];
    const float* b_hh     = (const float*)d_in[16];
    const float* fcn_w    = (const float*)d_in[17];
    const float* fcn_b    = (const float*)d_in[18];
    float* out = (float*)d_out;
    char* wsb  = (char*)d_ws;

    size_t off = 0;
    __hip_bfloat16* Uf    = (__hip_bfloat16*)(wsb + off); off += (size_t)B * P * ATT * 2;    // 12.8MB
    __hip_bfloat16* featT = (__hip_bfloat16*)(wsb + off); off += (size_t)B * ENC * PP * 2;   // 26.2MB
    __hip_bfloat16* Wa_wb = (__hip_bfloat16*)(wsb + off); off += (size_t)DEC * ATT * 2;
    float* partials = (float*)(wsb + off); off += (size_t)KS * B * NG * 4;                   // 8.4MB
    float* hbuf     = (float*)(wsb + off); off += (size_t)B * DEC * 4;
    float* cbufA    = (float*)(wsb + off); off += (size_t)B * DEC * 4;
    float* cbufB    = (float*)(wsb + off); off += (size_t)B * DEC * 4;
    float* ctxp     = (float*)(wsb + off); off += (size_t)2 * B * ENC * 4;
    float* mlp      = (float*)(wsb + off); off += 4096;
    float* meanf    = ctxp;   // alias: meanf used only before ctxp's first use
    size_t need_min = off;
    float* Hall     = (float*)(wsb + off); off += (size_t)S * B * DEC * 4;                   // 67MB
    size_t need_hall = off;
    __hip_bfloat16* Gemb = (__hip_bfloat16*)(wsb + off);
    off += (size_t)S * B * NG * 2;                                                           // 134MB
    size_t need_gemb = off;

    (void)need_min;
    int use_hall = ws_size >= need_hall;
    int use_gemb = ws_size >= need_gemb;

    k_mean<<<256, 256, 0, stream>>>(features, meanf);
    k_init_hc<<<256, 256, 0, stream>>>(meanf, ih_w, ih_b, ic_w, ic_b, hbuf, cbufA);
    k_uf<<<3136, 256, 0, stream>>>(features, Ua_w, Ua_b, Uf);
    k_featT<<<dim3(128, 25), 512, 0, stream>>>(features, featT);
    k_wacvt<<<512, 256, 0, stream>>>(Wa_w, Wa_wb);
    if (use_gemb)
        k_gemb<<<dim3(256, 16), 256, 0, stream>>>(emb, captions, W_ih, Gemb);

    for (int t = 0; t <= S; ++t) {
        // c ping-pong: initial c in cbufA (t=1 reads A, writes B; t=2 reads B...)
        const float* crd = (t & 1) ? cbufA : cbufB;
        float*       cwr = (t & 1) ? cbufB : cbufA;
        k_attn_cell<<<256, 512, 0, stream>>>(partials, Gemb, b_ih, b_hh,
                hbuf, crd, cwr, Hall, Wa_wb, Wa_b, Uf, featT, va_w, va_b,
                ctxp, mlp, t, use_gemb, use_hall);
        if (t < S)
            k_gates<<<dim3(32, KS), 256, 0, stream>>>(emb, captions, t, ctxp, mlp,
                    hbuf, W_ih, W_hh, partials, use_gemb);
        if (!use_hall && t > 0)
            k_fcn<<<dim3(1, 40), 256, 0, stream>>>(hbuf, fcn_w, fcn_b, out, t - 1);
    }
    if (use_hall)
        k_fcn<<<dim3(256, 40), 256, 0, stream>>>(Hall, fcn_w, fcn_b, out, -1);
}

// Round 7
// 14774.805 us; speedup vs baseline: 1.1790x; 1.1790x over previous
//
#include <hip/hip_runtime.h>
#include <hip/hip_bf16.h>

#define B 128
#define P 196
#define PP 200       // padded P (bf16 rows 400B, 16B-aligned)
#define ENC 512
#define DEC 512
#define ATT 256
#define EMB 256
#define V 5000
#define S 256
#define S1 257
#define NG 2048      // 4*DEC
#define KS 16        // k-splits for gates GEMM

typedef __attribute__((ext_vector_type(4))) short s4v;
typedef __attribute__((ext_vector_type(8))) short s8v;

__device__ __forceinline__ float bf2f(short u) {
    unsigned int x = ((unsigned int)(unsigned short)u) << 16;
    float f; __builtin_memcpy(&f, &x, 4); return f;
}

// ---------------- mean over P ----------------
__global__ __launch_bounds__(256) void k_mean(const float* __restrict__ feat,
                                              float* __restrict__ mean_f) {
    int idx = blockIdx.x * 256 + threadIdx.x;
    int b = idx >> 9, e = idx & 511;
    const float* fp = feat + (size_t)b * P * ENC + e;
    float s = 0.f;
    for (int p = 0; p < P; ++p) s += fp[(size_t)p * ENC];
    mean_f[idx] = s * (1.0f / (float)P);
}

// ---------------- h0 / c0 ----------------
__global__ __launch_bounds__(256) void k_init_hc(const float* __restrict__ mean_f,
        const float* __restrict__ ih_w, const float* __restrict__ ih_b,
        const float* __restrict__ ic_w, const float* __restrict__ ic_b,
        float* __restrict__ h, float* __restrict__ c) {
    int idx = blockIdx.x * 256 + threadIdx.x;
    int b = idx >> 9, d = idx & 511;
    const float* mf = mean_f + (size_t)b * ENC;
    float sh = ih_b[d], sc = ic_b[d];
    for (int e = 0; e < ENC; ++e) {
        float m = mf[e];
        sh = fmaf(m, ih_w[(size_t)e * DEC + d], sh);
        sc = fmaf(m, ic_w[(size_t)e * DEC + d], sc);
    }
    h[idx] = sh; c[idx] = sc;
}

// ---------------- Uf = features @ Ua_w + Ua_b  (bf16 out) ----------------
__global__ __launch_bounds__(256) void k_uf(const float* __restrict__ feat,
        const float* __restrict__ Ua_w, const float* __restrict__ Ua_b,
        __hip_bfloat16* __restrict__ Uf) {
    int row0 = blockIdx.x * 8;
    int a = threadIdx.x;
    __shared__ float fs[8][ENC];
    for (int i = threadIdx.x; i < 8 * ENC; i += 256) {
        int r = i >> 9, e = i & 511;
        fs[r][e] = feat[(size_t)(row0 + r) * ENC + e];
    }
    __syncthreads();
    float acc[8];
    float bia = Ua_b[a];
#pragma unroll
    for (int r = 0; r < 8; ++r) acc[r] = bia;
    for (int e = 0; e < ENC; ++e) {
        float w = Ua_w[(size_t)e * ATT + a];
#pragma unroll
        for (int r = 0; r < 8; ++r) acc[r] = fmaf(fs[r][e], w, acc[r]);
    }
#pragma unroll
    for (int r = 0; r < 8; ++r)
        Uf[(size_t)(row0 + r) * ATT + a] = __float2bfloat16(acc[r]);
}

// ---------------- featT[b][e][p] bf16, zero-padded to PP ----------------
__global__ __launch_bounds__(512) void k_featT(const float* __restrict__ feat,
        __hip_bfloat16* __restrict__ featT) {
    int b = blockIdx.x, p0 = blockIdx.y * 8;
    int e = threadIdx.x;
    __hip_bfloat16 v[8];
#pragma unroll
    for (int i = 0; i < 8; ++i) {
        int p = p0 + i;
        float f = (p < P) ? feat[((size_t)b * P + p) * ENC + e] : 0.f;
        v[i] = __float2bfloat16(f);
    }
    __builtin_memcpy(&featT[((size_t)b * ENC + e) * PP + p0], v, 16);
}

// ---------------- Wa_w -> bf16 ----------------
__global__ __launch_bounds__(256) void k_wacvt(const float* __restrict__ w,
        __hip_bfloat16* __restrict__ wb) {
    int i = blockIdx.x * 256 + threadIdx.x;   // DEC*ATT = 131072
    wb[i] = __float2bfloat16(w[i]);
}

// ---------------- Gemb = embeds[:, :S] @ W_ih[:EMB]  (bf16 out) ----------------
__global__ __launch_bounds__(256) void k_gemb(const float* __restrict__ emb,
        const int* __restrict__ captions, const float* __restrict__ W_ih,
        __hip_bfloat16* __restrict__ Gemb) {
    __shared__ float As[16][128];
    __shared__ float Bs[16][128];
    __shared__ int rowcap[128];
    int m0 = blockIdx.x * 128;
    int n0 = blockIdx.y * 128;
    int tid = threadIdx.x;
    if (tid < 128) {
        int m = m0 + tid;
        rowcap[tid] = captions[(size_t)(m & 127) * S1 + (m >> 7)];
    }
    __syncthreads();
    int tx = tid & 15, ty = tid >> 4;
    float acc[8][8];
#pragma unroll
    for (int i = 0; i < 8; ++i)
#pragma unroll
        for (int j = 0; j < 8; ++j) acc[i][j] = 0.f;
    int arow = tid >> 1, ak = (tid & 1) * 8;
    int bkk = tid >> 4, bn = (tid & 15) * 8;
    for (int k0 = 0; k0 < EMB; k0 += 16) {
        {
            const float* ap = emb + (size_t)rowcap[arow] * EMB + k0 + ak;
            float4 v0 = *(const float4*)ap;
            float4 v1 = *(const float4*)(ap + 4);
            As[ak + 0][arow] = v0.x; As[ak + 1][arow] = v0.y;
            As[ak + 2][arow] = v0.z; As[ak + 3][arow] = v0.w;
            As[ak + 4][arow] = v1.x; As[ak + 5][arow] = v1.y;
            As[ak + 6][arow] = v1.z; As[ak + 7][arow] = v1.w;
        }
        {
            const float* bp = W_ih + (size_t)(k0 + bkk) * NG + n0 + bn;
            *(float4*)&Bs[bkk][bn] = *(const float4*)bp;
            *(float4*)&Bs[bkk][bn + 4] = *(const float4*)(bp + 4);
        }
        __syncthreads();
#pragma unroll
        for (int kk = 0; kk < 16; ++kk) {
            float4 a0 = *(const float4*)&As[kk][ty * 8];
            float4 a1 = *(const float4*)&As[kk][ty * 8 + 4];
            float4 b0 = *(const float4*)&Bs[kk][tx * 8];
            float4 b1 = *(const float4*)&Bs[kk][tx * 8 + 4];
            float av[8] = {a0.x, a0.y, a0.z, a0.w, a1.x, a1.y, a1.z, a1.w};
            float bv[8] = {b0.x, b0.y, b0.z, b0.w, b1.x, b1.y, b1.z, b1.w};
#pragma unroll
            for (int i = 0; i < 8; ++i)
#pragma unroll
                for (int j = 0; j < 8; ++j)
                    acc[i][j] = fmaf(av[i], bv[j], acc[i][j]);
        }
        __syncthreads();
    }
#pragma unroll
    for (int i = 0; i < 8; ++i) {
        __hip_bfloat16* gp = Gemb + (size_t)(m0 + ty * 8 + i) * NG + n0 + tx * 8;
#pragma unroll
        for (int j = 0; j < 8; ++j) gp[j] = __float2bfloat16(acc[i][j]);
    }
}

// ======== fused: cell (reduce partials) + wah + half-attention ========
// 256 blocks (b, half) x 1024 threads (16 waves/CU = 4 waves/SIMD).
// Both halves redo the cell; only half 0 writes h/c/Hall. c ping-pong.
// t==0: no cell. t==S: cell only.
__global__ __launch_bounds__(1024) void k_attn_cell(
        const float* __restrict__ partials, const __hip_bfloat16* __restrict__ Gemb,
        const float* __restrict__ b_ih, const float* __restrict__ b_hh,
        float* __restrict__ h, const float* __restrict__ cr, float* __restrict__ cw,
        float* __restrict__ Hall,
        const __hip_bfloat16* __restrict__ Wa_wb, const float* __restrict__ Wa_b,
        const __hip_bfloat16* __restrict__ Uf, const __hip_bfloat16* __restrict__ featT,
        const float* __restrict__ va_w, const float* __restrict__ va_b,
        float* __restrict__ ctxp, float* __restrict__ mlp,
        int t, int use_gemb, int use_hall) {
    int g = blockIdx.x;
    int b = g >> 1, half = g & 1;
    int tid = threadIdx.x;
    int base = half ? 96 : 0;
    int cnt  = half ? 100 : 96;    // real positions
    __shared__ float hs[DEC];
    __shared__ float wahp[4][ATT];
    __shared__ float wahs[ATT];
    __shared__ float sc[104];
    __shared__ float red[4];
    __shared__ float cpart[2][ENC];

    // ---- cell (tid < 512) ----
    if (t > 0) {
        if (tid < DEC) {
            int d = tid;
            float s0 = b_ih[d]           + b_hh[d];
            float s1 = b_ih[d + DEC]     + b_hh[d + DEC];
            float s2 = b_ih[d + 2 * DEC] + b_hh[d + 2 * DEC];
            float s3 = b_ih[d + 3 * DEC] + b_hh[d + 3 * DEC];
#pragma unroll
            for (int ks = 0; ks < KS; ++ks) {
                const float* pp = partials + ((size_t)ks * B + b) * NG + d;
                s0 += pp[0]; s1 += pp[DEC]; s2 += pp[2 * DEC]; s3 += pp[3 * DEC];
            }
            if (use_gemb) {
                const __hip_bfloat16* gp = Gemb + ((size_t)(t - 1) * B + b) * NG + d;
                s0 += __bfloat162float(gp[0]);
                s1 += __bfloat162float(gp[DEC]);
                s2 += __bfloat162float(gp[2 * DEC]);
                s3 += __bfloat162float(gp[3 * DEC]);
            }
            size_t gidx = (size_t)b * DEC + d;
            float ii = 1.f / (1.f + __expf(-s0));
            float ff = 1.f / (1.f + __expf(-s1));
            float gg = tanhf(s2);
            float oo = 1.f / (1.f + __expf(-s3));
            float cn = ff * cr[gidx] + ii * gg;
            float hn = oo * tanhf(cn);
            hs[d] = hn;
            if (half == 0) {
                cw[gidx] = cn;
                h[gidx] = hn;
                if (use_hall) Hall[((size_t)(t - 1) * B + b) * DEC + d] = hn;
            }
        }
    } else {
        if (tid < DEC) hs[tid] = h[(size_t)b * DEC + tid];
    }
    __syncthreads();
    if (t == S) return;

    // ---- wah GEMV: thread (a, q) covers d in [q*128, q*128+128) ----
    {
        int a = tid & 255, q = tid >> 8;
        float acc = 0.f;
        const __hip_bfloat16* wp = Wa_wb + (size_t)(q * 128) * ATT + a;
        const float* hq = &hs[q * 128];
#pragma unroll 4
        for (int dd = 0; dd < 128; ++dd)
            acc = fmaf(hq[dd], bf2f(*(const short*)&wp[(size_t)dd * ATT]), acc);
        wahp[q][a] = acc;
    }
    __syncthreads();
    if (tid < ATT)
        wahs[tid] = Wa_b[tid] + wahp[0][tid] + wahp[1][tid] + wahp[2][tid] + wahp[3][tid];
    __syncthreads();

    // ---- scores: 16 waves, local pl stride-16; lane covers 4 a's ----
    {
        int w = tid >> 6, lane = tid & 63;
        float4 wv = *(const float4*)&wahs[lane * 4];
        float4 vv = *(const float4*)&va_w[lane * 4];
        float vb = va_b[0];
        for (int pl = w; pl < cnt; pl += 16) {
            const __hip_bfloat16* ufp = Uf + ((size_t)b * P + base + pl) * ATT + lane * 4;
            s4v u4 = *(const s4v*)ufp;
            float ssc = vv.x * tanhf(bf2f(u4.x) + wv.x) + vv.y * tanhf(bf2f(u4.y) + wv.y)
                      + vv.z * tanhf(bf2f(u4.z) + wv.z) + vv.w * tanhf(bf2f(u4.w) + wv.w);
#pragma unroll
            for (int off = 32; off; off >>= 1) ssc += __shfl_down(ssc, off);
            if (lane == 0) sc[pl] = ssc + vb;
        }
    }
    __syncthreads();

    // ---- local softmax over cnt ----
    {
        int lane = tid & 63;
        float v = (tid < cnt) ? sc[tid] : -1e30f;
        if (tid < 128) {
            float m = v;
#pragma unroll
            for (int off = 32; off; off >>= 1) m = fmaxf(m, __shfl_down(m, off));
            if (lane == 0) red[tid >> 6] = m;
        }
        __syncthreads();
        float mh = fmaxf(red[0], red[1]);
        float e = (tid < cnt) ? __expf(v - mh) : 0.f;
        if (tid < 128) {
            float l = e;
#pragma unroll
            for (int off = 32; off; off >>= 1) l += __shfl_down(l, off);
            if (lane == 0) red[2 + (tid >> 6)] = l;
        }
        __syncthreads();
        if (tid < cnt) sc[tid] = e;
        else if (tid < 104) sc[tid] = 0.f;
        if (tid == 0) {
            mlp[((size_t)half * B + b) * 2 + 0] = mh;
            mlp[((size_t)half * B + b) * 2 + 1] = red[2] + red[3];
        }
    }
    __syncthreads();

    // ---- partial (unnormalized) context: (e, ph) split over p-chunks ----
    {
        int e = tid & 511, ph = tid >> 9;
        // half0: 12 chunks -> ph0: 0..5, ph1: 6..11
        // half1: 13 chunks -> ph0: 0..6, ph1: 7..12
        int start = half ? (ph ? 7 : 0) : (ph ? 6 : 0);
        int nch   = half ? (ph ? 6 : 7) : 6;
        float acc = 0.f;
        const __hip_bfloat16* fr = featT + ((size_t)b * ENC + e) * PP + base + start * 8;
        for (int ch = 0; ch < nch; ++ch) {
            s8v raw = *(const s8v*)(fr + ch * 8);
            const float* sp = &sc[(start + ch) * 8];
#pragma unroll
            for (int j = 0; j < 8; ++j)
                acc = fmaf(sp[j], bf2f(raw[j]), acc);
        }
        cpart[ph][e] = acc;
    }
    __syncthreads();
    if (tid < ENC)
        ctxp[((size_t)half * B + b) * ENC + tid] = cpart[0][tid] + cpart[1][tid];
}

// ---------------- gates partial GEMM with inline ctx combine ----------------
// grid (32 n-tiles, KS=16) = 512 blocks x 256 thr -> 2 blocks/CU, 2 waves/SIMD
__global__ __launch_bounds__(256) void k_gates(const float* __restrict__ emb,
        const int* __restrict__ captions, int t,
        const float* __restrict__ ctxp, const float* __restrict__ mlp,
        const float* __restrict__ h,
        const float* __restrict__ W_ih, const float* __restrict__ W_hh,
        float* __restrict__ partials, int use_gemb) {
    __shared__ float As[16][128];
    __shared__ float Bs[16][64];
    __shared__ float sw0[B], sw1[B];
    __shared__ int scap[B];
    int n0 = blockIdx.x * 64;
    int ks = blockIdx.y;
    int tid = threadIdx.x;
    int kch = use_gemb ? 64 : 80;
    if (tid < B) {
        float m0 = mlp[(size_t)tid * 2 + 0];
        float l0 = mlp[(size_t)tid * 2 + 1];
        float m1 = mlp[((size_t)B + tid) * 2 + 0];
        float l1 = mlp[((size_t)B + tid) * 2 + 1];
        float M = fmaxf(m0, m1);
        float e0 = __expf(m0 - M), e1 = __expf(m1 - M);
        float inv = 1.f / (l0 * e0 + l1 * e1);
        sw0[tid] = e0 * inv; sw1[tid] = e1 * inv;
        if (!use_gemb) scap[tid] = captions[(size_t)tid * S1 + t];
    }
    __syncthreads();
    int tx = tid & 15, ty = tid >> 4;
    float acc[8][4];
#pragma unroll
    for (int i = 0; i < 8; ++i)
#pragma unroll
        for (int j = 0; j < 4; ++j) acc[i][j] = 0.f;
    int arow = tid >> 1, ak = (tid & 1) * 8;
    int bkk = tid >> 4, bn = (tid & 15) * 4;
    for (int k0 = ks * kch; k0 < ks * kch + kch; k0 += 16) {
        {
            int k = k0 + ak;
            if (!use_gemb && k < EMB) {
                const float* ap = emb + (size_t)scap[arow] * EMB + k;
                float4 v0 = *(const float4*)ap;
                float4 v1 = *(const float4*)(ap + 4);
                As[ak + 0][arow] = v0.x; As[ak + 1][arow] = v0.y;
                As[ak + 2][arow] = v0.z; As[ak + 3][arow] = v0.w;
                As[ak + 4][arow] = v1.x; As[ak + 5][arow] = v1.y;
                As[ak + 6][arow] = v1.z; As[ak + 7][arow] = v1.w;
            } else {
                int kc = use_gemb ? k : (k - EMB);
                if (kc < ENC) {
                    const float* p0 = ctxp + (size_t)arow * ENC + kc;
                    const float* p1 = ctxp + ((size_t)B + arow) * ENC + kc;
                    float w0 = sw0[arow], w1 = sw1[arow];
                    float4 a0 = *(const float4*)p0;
                    float4 a1 = *(const float4*)(p0 + 4);
                    float4 b0 = *(const float4*)p1;
                    float4 b1 = *(const float4*)(p1 + 4);
                    As[ak + 0][arow] = a0.x * w0 + b0.x * w1;
                    As[ak + 1][arow] = a0.y * w0 + b0.y * w1;
                    As[ak + 2][arow] = a0.z * w0 + b0.z * w1;
                    As[ak + 3][arow] = a0.w * w0 + b0.w * w1;
                    As[ak + 4][arow] = a1.x * w0 + b1.x * w1;
                    As[ak + 5][arow] = a1.y * w0 + b1.y * w1;
                    As[ak + 6][arow] = a1.z * w0 + b1.z * w1;
                    As[ak + 7][arow] = a1.w * w0 + b1.w * w1;
                } else {
                    const float* ap = h + (size_t)arow * DEC + (kc - ENC);
                    float4 v0 = *(const float4*)ap;
                    float4 v1 = *(const float4*)(ap + 4);
                    As[ak + 0][arow] = v0.x; As[ak + 1][arow] = v0.y;
                    As[ak + 2][arow] = v0.z; As[ak + 3][arow] = v0.w;
                    As[ak + 4][arow] = v1.x; As[ak + 5][arow] = v1.y;
                    As[ak + 6][arow] = v1.z; As[ak + 7][arow] = v1.w;
                }
            }
        }
        {
            int k = k0 + bkk;
            const float* bp;
            if (use_gemb)
                bp = (k < ENC) ? W_ih + (size_t)(k + EMB) * NG + n0 + bn
                               : W_hh + (size_t)(k - ENC) * NG + n0 + bn;
            else
                bp = (k < EMB + ENC) ? W_ih + (size_t)k * NG + n0 + bn
                                     : W_hh + (size_t)(k - EMB - ENC) * NG + n0 + bn;
            *(float4*)&Bs[bkk][bn] = *(const float4*)bp;
        }
        __syncthreads();
#pragma unroll
        for (int kk = 0; kk < 16; ++kk) {
            float4 a0 = *(const float4*)&As[kk][ty * 8];
            float4 a1 = *(const float4*)&As[kk][ty * 8 + 4];
            float4 b0 = *(const float4*)&Bs[kk][tx * 4];
            float av[8] = {a0.x, a0.y, a0.z, a0.w, a1.x, a1.y, a1.z, a1.w};
            float bv[4] = {b0.x, b0.y, b0.z, b0.w};
#pragma unroll
            for (int i = 0; i < 8; ++i)
#pragma unroll
                for (int j = 0; j < 4; ++j)
                    acc[i][j] = fmaf(av[i], bv[j], acc[i][j]);
        }
        __syncthreads();
    }
#pragma unroll
    for (int i = 0; i < 8; ++i) {
        int mrow = ty * 8 + i;
        float* pp = partials + ((size_t)ks * B + mrow) * NG + n0 + tx * 4;
        *(float4*)pp = make_float4(acc[i][0], acc[i][1], acc[i][2], acc[i][3]);
    }
}

// ---------------- output projection GEMM ----------------
__global__ __launch_bounds__(256) void k_fcn(const float* __restrict__ A,
        const float* __restrict__ Bw, const float* __restrict__ bias,
        float* __restrict__ out, int t_fix) {
    __shared__ float As[16][128];
    __shared__ float Bs[16][128];
    int m0 = blockIdx.x * 128;
    int n0 = blockIdx.y * 128;
    int tid = threadIdx.x;
    int tx = tid & 15, ty = tid >> 4;
    float acc[8][8];
#pragma unroll
    for (int i = 0; i < 8; ++i)
#pragma unroll
        for (int j = 0; j < 8; ++j) acc[i][j] = 0.f;
    int arow = tid >> 1, ak = (tid & 1) * 8;
    int bkk = tid >> 4, bn = (tid & 15) * 8;
    const float4 z4 = make_float4(0.f, 0.f, 0.f, 0.f);
    for (int k0 = 0; k0 < DEC; k0 += 16) {
        {
            const float* ap = A + (size_t)(m0 + arow) * DEC + k0 + ak;
            float4 v0 = *(const float4*)ap;
            float4 v1 = *(const float4*)(ap + 4);
            As[ak + 0][arow] = v0.x; As[ak + 1][arow] = v0.y;
            As[ak + 2][arow] = v0.z; As[ak + 3][arow] = v0.w;
            As[ak + 4][arow] = v1.x; As[ak + 5][arow] = v1.y;
            As[ak + 6][arow] = v1.z; As[ak + 7][arow] = v1.w;
        }
        {
            int n4 = n0 + bn;
            const float* bp = Bw + (size_t)(k0 + bkk) * V + n4;
            float4 v0 = (n4 < V) ? *(const float4*)bp : z4;
            float4 v1 = (n4 + 4 < V) ? *(const float4*)(bp + 4) : z4;
            *(float4*)&Bs[bkk][bn] = v0;
            *(float4*)&Bs[bkk][bn + 4] = v1;
        }
        __syncthreads();
#pragma unroll
        for (int kk = 0; kk < 16; ++kk) {
            float4 a0 = *(const float4*)&As[kk][ty * 8];
            float4 a1 = *(const float4*)&As[kk][ty * 8 + 4];
            float4 b0 = *(const float4*)&Bs[kk][tx * 8];
            float4 b1 = *(const float4*)&Bs[kk][tx * 8 + 4];
            float av[8] = {a0.x, a0.y, a0.z, a0.w, a1.x, a1.y, a1.z, a1.w};
            float bv[8] = {b0.x, b0.y, b0.z, b0.w, b1.x, b1.y, b1.z, b1.w};
#pragma unroll
            for (int i = 0; i < 8; ++i)
#pragma unroll
                for (int j = 0; j < 8; ++j)
                    acc[i][j] = fmaf(av[i], bv[j], acc[i][j]);
        }
        __syncthreads();
    }
#pragma unroll
    for (int i = 0; i < 8; ++i) {
        int mrow = m0 + ty * 8 + i;
        int bb, tt;
        if (t_fix >= 0) { bb = mrow; tt = t_fix; }
        else            { tt = mrow >> 7; bb = mrow & 127; }
        float* op = out + ((size_t)bb * S + tt) * V + n0 + tx * 8;
#pragma unroll
        for (int j = 0; j < 8; ++j) {
            int n = n0 + tx * 8 + j;
            if (n < V) op[j] = acc[i][j] + bias[n];
        }
    }
}

extern "C" void kernel_launch(void* const* d_in, const int* in_sizes, int n_in,
                              void* d_out, int out_size, void* d_ws, size_t ws_size,
                              hipStream_t stream) {
    const float* features = (const float*)d_in[0];
    const int*   captions = (const int*)d_in[1];
    const float* emb      = (const float*)d_in[2];
    const float* Ua_w     = (const float*)d_in[3];
    const float* Ua_b     = (const float*)d_in[4];
    const float* Wa_w     = (const float*)d_in[5];
    const float* Wa_b     = (const float*)d_in[6];
    const float* va_w     = (const float*)d_in[7];
    const float* va_b     = (const float*)d_in[8];
    const float* ih_w     = (const float*)d_in[9];
    const float* ih_b     = (const float*)d_in[10];
    const float* ic_w     = (const float*)d_in[11];
    const float* ic_b     = (const float*)d_in[12];
    const float* W_ih     = (const float*)d_in[13];
    const float* b_ih     = (const float*)d_in[14];
    const float* W_hh     = (const float*)d_in[15];
    const float* b_hh     = (const float*)d_in[16];
    const float* fcn_w    = (const float*)d_in[17];
    const float* fcn_b    = (const float*)d_in[18];
    float* out = (float*)d_out;
    char* wsb  = (char*)d_ws;

    size_t off = 0;
    __hip_bfloat16* Uf    = (__hip_bfloat16*)(wsb + off); off += (size_t)B * P * ATT * 2;    // 12.8MB
    __hip_bfloat16* featT = (__hip_bfloat16*)(wsb + off); off += (size_t)B * ENC * PP * 2;   // 26.2MB
    __hip_bfloat16* Wa_wb = (__hip_bfloat16*)(wsb + off); off += (size_t)DEC * ATT * 2;
    float* partials = (float*)(wsb + off); off += (size_t)KS * B * NG * 4;                   // 16.8MB
    float* hbuf     = (float*)(wsb + off); off += (size_t)B * DEC * 4;
    float* cbufA    = (float*)(wsb + off); off += (size_t)B * DEC * 4;
    float* cbufB    = (float*)(wsb + off); off += (size_t)B * DEC * 4;
    float* ctxp     = (float*)(wsb + off); off += (size_t)2 * B * ENC * 4;
    float* mlp      = (float*)(wsb + off); off += 4096;
    float* meanf    = ctxp;   // alias: meanf used only before ctxp's first use
    size_t need_min = off;
    float* Hall     = (float*)(wsb + off); off += (size_t)S * B * DEC * 4;                   // 67MB
    size_t need_hall = off;
    __hip_bfloat16* Gemb = (__hip_bfloat16*)(wsb + off);
    off += (size_t)S * B * NG * 2;                                                           // 134MB
    size_t need_gemb = off;

    (void)need_min;
    int use_hall = ws_size >= need_hall;
    int use_gemb = ws_size >= need_gemb;

    k_mean<<<256, 256, 0, stream>>>(features, meanf);
    k_init_hc<<<256, 256, 0, stream>>>(meanf, ih_w, ih_b, ic_w, ic_b, hbuf, cbufA);
    k_uf<<<3136, 256, 0, stream>>>(features, Ua_w, Ua_b, Uf);
    k_featT<<<dim3(128, 25), 512, 0, stream>>>(features, featT);
    k_wacvt<<<512, 256, 0, stream>>>(Wa_w, Wa_wb);
    if (use_gemb)
        k_gemb<<<dim3(256, 16), 256, 0, stream>>>(emb, captions, W_ih, Gemb);

    for (int t = 0; t <= S; ++t) {
        // c ping-pong: initial c in cbufA (t=1 reads A, writes B; t=2 reads B...)
        const float* crd = (t & 1) ? cbufA : cbufB;
        float*       cwr = (t & 1) ? cbufB : cbufA;
        k_attn_cell<<<256, 1024, 0, stream>>>(partials, Gemb, b_ih, b_hh,
                hbuf, crd, cwr, Hall, Wa_wb, Wa_b, Uf, featT, va_w, va_b,
                ctxp, mlp, t, use_gemb, use_hall);
        if (t < S)
            k_gates<<<dim3(32, KS), 256, 0, stream>>>(emb, captions, t, ctxp, mlp,
                    hbuf, W_ih, W_hh, partials, use_gemb);
        if (!use_hall && t > 0)
            k_fcn<<<dim3(1, 40), 256, 0, stream>>>(hbuf, fcn_w, fcn_b, out, t - 1);
    }
    if (use_hall)
        k_fcn<<<dim3(256, 40), 256, 0, stream>>>(Hall, fcn_w, fcn_b, out, -1);
}

// Round 8
// 14107.054 us; speedup vs baseline: 1.2348x; 1.0473x over previous
//
#include <hip/hip_runtime.h>
#include <hip/hip_bf16.h>

#define B 128
#define P 196
#define PP 200       // padded P (bf16 rows 400B, 16B-aligned)
#define ENC 512
#define DEC 512
#define ATT 256
#define EMB 256
#define V 5000
#define S 256
#define S1 257
#define NG 2048      // 4*DEC
#define KS 16        // k-splits for gates GEMM

typedef __attribute__((ext_vector_type(4))) short s4v;
typedef __attribute__((ext_vector_type(8))) short s8v;

__device__ __forceinline__ float bf2f(short u) {
    unsigned int x = ((unsigned int)(unsigned short)u) << 16;
    float f; __builtin_memcpy(&f, &x, 4); return f;
}

// fast tanh: (e^2x - 1) / (e^2x + 1), clamp to avoid inf/inf
__device__ __forceinline__ float tanhf_fast(float x) {
    float xx = fminf(fmaxf(x, -15.f), 15.f);
    float t = __expf(2.f * xx);
    return (t - 1.f) * __builtin_amdgcn_rcpf(t + 1.f);
}

// ---------------- mean over P ----------------
__global__ __launch_bounds__(256) void k_mean(const float* __restrict__ feat,
                                              float* __restrict__ mean_f) {
    int idx = blockIdx.x * 256 + threadIdx.x;
    int b = idx >> 9, e = idx & 511;
    const float* fp = feat + (size_t)b * P * ENC + e;
    float s = 0.f;
    for (int p = 0; p < P; ++p) s += fp[(size_t)p * ENC];
    mean_f[idx] = s * (1.0f / (float)P);
}

// ---------------- h0 / c0 ----------------
__global__ __launch_bounds__(256) void k_init_hc(const float* __restrict__ mean_f,
        const float* __restrict__ ih_w, const float* __restrict__ ih_b,
        const float* __restrict__ ic_w, const float* __restrict__ ic_b,
        float* __restrict__ h, float* __restrict__ c) {
    int idx = blockIdx.x * 256 + threadIdx.x;
    int b = idx >> 9, d = idx & 511;
    const float* mf = mean_f + (size_t)b * ENC;
    float sh = ih_b[d], sc = ic_b[d];
    for (int e = 0; e < ENC; ++e) {
        float m = mf[e];
        sh = fmaf(m, ih_w[(size_t)e * DEC + d], sh);
        sc = fmaf(m, ic_w[(size_t)e * DEC + d], sc);
    }
    h[idx] = sh; c[idx] = sc;
}

// ---------------- Uf = features @ Ua_w + Ua_b  (bf16 out) ----------------
__global__ __launch_bounds__(256) void k_uf(const float* __restrict__ feat,
        const float* __restrict__ Ua_w, const float* __restrict__ Ua_b,
        __hip_bfloat16* __restrict__ Uf) {
    int row0 = blockIdx.x * 8;
    int a = threadIdx.x;
    __shared__ float fs[8][ENC];
    for (int i = threadIdx.x; i < 8 * ENC; i += 256) {
        int r = i >> 9, e = i & 511;
        fs[r][e] = feat[(size_t)(row0 + r) * ENC + e];
    }
    __syncthreads();
    float acc[8];
    float bia = Ua_b[a];
#pragma unroll
    for (int r = 0; r < 8; ++r) acc[r] = bia;
    for (int e = 0; e < ENC; ++e) {
        float w = Ua_w[(size_t)e * ATT + a];
#pragma unroll
        for (int r = 0; r < 8; ++r) acc[r] = fmaf(fs[r][e], w, acc[r]);
    }
#pragma unroll
    for (int r = 0; r < 8; ++r)
        Uf[(size_t)(row0 + r) * ATT + a] = __float2bfloat16(acc[r]);
}

// ---------------- featT[b][e][p] bf16, zero-padded to PP ----------------
__global__ __launch_bounds__(512) void k_featT(const float* __restrict__ feat,
        __hip_bfloat16* __restrict__ featT) {
    int b = blockIdx.x, p0 = blockIdx.y * 8;
    int e = threadIdx.x;
    __hip_bfloat16 v[8];
#pragma unroll
    for (int i = 0; i < 8; ++i) {
        int p = p0 + i;
        float f = (p < P) ? feat[((size_t)b * P + p) * ENC + e] : 0.f;
        v[i] = __float2bfloat16(f);
    }
    __builtin_memcpy(&featT[((size_t)b * ENC + e) * PP + p0], v, 16);
}

// ---------------- Wa_w -> bf16 ----------------
__global__ __launch_bounds__(256) void k_wacvt(const float* __restrict__ w,
        __hip_bfloat16* __restrict__ wb) {
    int i = blockIdx.x * 256 + threadIdx.x;   // DEC*ATT = 131072
    wb[i] = __float2bfloat16(w[i]);
}

// ---------------- Gemb = embeds[:, :S] @ W_ih[:EMB]  (bf16 out) ----------------
__global__ __launch_bounds__(256) void k_gemb(const float* __restrict__ emb,
        const int* __restrict__ captions, const float* __restrict__ W_ih,
        __hip_bfloat16* __restrict__ Gemb) {
    __shared__ float As[16][128];
    __shared__ float Bs[16][128];
    __shared__ int rowcap[128];
    int m0 = blockIdx.x * 128;
    int n0 = blockIdx.y * 128;
    int tid = threadIdx.x;
    if (tid < 128) {
        int m = m0 + tid;
        rowcap[tid] = captions[(size_t)(m & 127) * S1 + (m >> 7)];
    }
    __syncthreads();
    int tx = tid & 15, ty = tid >> 4;
    float acc[8][8];
#pragma unroll
    for (int i = 0; i < 8; ++i)
#pragma unroll
        for (int j = 0; j < 8; ++j) acc[i][j] = 0.f;
    int arow = tid >> 1, ak = (tid & 1) * 8;
    int bkk = tid >> 4, bn = (tid & 15) * 8;
    for (int k0 = 0; k0 < EMB; k0 += 16) {
        {
            const float* ap = emb + (size_t)rowcap[arow] * EMB + k0 + ak;
            float4 v0 = *(const float4*)ap;
            float4 v1 = *(const float4*)(ap + 4);
            As[ak + 0][arow] = v0.x; As[ak + 1][arow] = v0.y;
            As[ak + 2][arow] = v0.z; As[ak + 3][arow] = v0.w;
            As[ak + 4][arow] = v1.x; As[ak + 5][arow] = v1.y;
            As[ak + 6][arow] = v1.z; As[ak + 7][arow] = v1.w;
        }
        {
            const float* bp = W_ih + (size_t)(k0 + bkk) * NG + n0 + bn;
            *(float4*)&Bs[bkk][bn] = *(const float4*)bp;
            *(float4*)&Bs[bkk][bn + 4] = *(const float4*)(bp + 4);
        }
        __syncthreads();
#pragma unroll
        for (int kk = 0; kk < 16; ++kk) {
            float4 a0 = *(const float4*)&As[kk][ty * 8];
            float4 a1 = *(const float4*)&As[kk][ty * 8 + 4];
            float4 b0 = *(const float4*)&Bs[kk][tx * 8];
            float4 b1 = *(const float4*)&Bs[kk][tx * 8 + 4];
            float av[8] = {a0.x, a0.y, a0.z, a0.w, a1.x, a1.y, a1.z, a1.w};
            float bv[8] = {b0.x, b0.y, b0.z, b0.w, b1.x, b1.y, b1.z, b1.w};
#pragma unroll
            for (int i = 0; i < 8; ++i)
#pragma unroll
                for (int j = 0; j < 8; ++j)
                    acc[i][j] = fmaf(av[i], bv[j], acc[i][j]);
        }
        __syncthreads();
    }
#pragma unroll
    for (int i = 0; i < 8; ++i) {
        __hip_bfloat16* gp = Gemb + (size_t)(m0 + ty * 8 + i) * NG + n0 + tx * 8;
#pragma unroll
        for (int j = 0; j < 8; ++j) gp[j] = __float2bfloat16(acc[i][j]);
    }
}

// ======== fused: cell + wah + half-attention, with Uf LDS prefetch ========
// 256 blocks (b, half) x 1024 threads. Threads 512-1023 prefetch this
// block's Uf slice into LDS while threads 0-511 run the LSTM cell.
__global__ __launch_bounds__(1024) void k_attn_cell(
        const float* __restrict__ partials, const __hip_bfloat16* __restrict__ Gemb,
        const float* __restrict__ b_ih, const float* __restrict__ b_hh,
        float* __restrict__ h, const float* __restrict__ cr, float* __restrict__ cw,
        float* __restrict__ Hall,
        const __hip_bfloat16* __restrict__ Wa_wb, const float* __restrict__ Wa_b,
        const __hip_bfloat16* __restrict__ Uf, const __hip_bfloat16* __restrict__ featT,
        const float* __restrict__ va_w, const float* __restrict__ va_b,
        float* __restrict__ ctxp, float* __restrict__ mlp,
        int t, int use_gemb, int use_hall) {
    int g = blockIdx.x;
    int b = g >> 1, half = g & 1;
    int tid = threadIdx.x;
    int base = half ? 96 : 0;
    int cnt  = half ? 100 : 96;    // real positions
    __shared__ short ufs[100][ATT];      // 51.2 KB bf16 Uf slice
    __shared__ float hs[DEC];
    __shared__ float wahp[4][ATT];
    __shared__ float wahs[ATT];
    __shared__ float sc[104];
    __shared__ float red[4];
    __shared__ float cpart[2][ENC];

    // ---- phase 0: cell (tid < 512) || Uf prefetch (tid >= 512) ----
    if (tid < 512) {
        if (t > 0) {
            int d = tid;
            float s0 = b_ih[d]           + b_hh[d];
            float s1 = b_ih[d + DEC]     + b_hh[d + DEC];
            float s2 = b_ih[d + 2 * DEC] + b_hh[d + 2 * DEC];
            float s3 = b_ih[d + 3 * DEC] + b_hh[d + 3 * DEC];
#pragma unroll
            for (int ks = 0; ks < KS; ++ks) {
                const float* pp = partials + ((size_t)ks * B + b) * NG + d;
                s0 += pp[0]; s1 += pp[DEC]; s2 += pp[2 * DEC]; s3 += pp[3 * DEC];
            }
            if (use_gemb) {
                const __hip_bfloat16* gp = Gemb + ((size_t)(t - 1) * B + b) * NG + d;
                s0 += __bfloat162float(gp[0]);
                s1 += __bfloat162float(gp[DEC]);
                s2 += __bfloat162float(gp[2 * DEC]);
                s3 += __bfloat162float(gp[3 * DEC]);
            }
            size_t gidx = (size_t)b * DEC + d;
            float ii = 1.f / (1.f + __expf(-s0));
            float ff = 1.f / (1.f + __expf(-s1));
            float gg = tanhf_fast(s2);
            float oo = 1.f / (1.f + __expf(-s3));
            float cn = ff * cr[gidx] + ii * gg;
            float hn = oo * tanhf_fast(cn);
            hs[d] = hn;
            if (half == 0) {
                cw[gidx] = cn;
                h[gidx] = hn;
                if (use_hall) Hall[((size_t)(t - 1) * B + b) * DEC + d] = hn;
            }
        } else {
            hs[tid] = h[(size_t)b * DEC + tid];
        }
    } else if (t < S) {
        // prefetch Uf slice [cnt][256] bf16 into LDS
        const __hip_bfloat16* ub = Uf + ((size_t)b * P + base) * ATT;
        for (int i = tid - 512; i < cnt * 32; i += 512) {
            int p = i >> 5, c = (i & 31) * 8;
            *(s8v*)&ufs[p][c] = *(const s8v*)(ub + (size_t)p * ATT + c);
        }
    }
    __syncthreads();
    if (t == S) return;

    // ---- wah GEMV: thread (a, q) covers d in [q*128, q*128+128) ----
    {
        int a = tid & 255, q = tid >> 8;
        float acc = 0.f;
        const __hip_bfloat16* wp = Wa_wb + (size_t)(q * 128) * ATT + a;
        const float* hq = &hs[q * 128];
#pragma unroll 4
        for (int dd = 0; dd < 128; ++dd)
            acc = fmaf(hq[dd], bf2f(*(const short*)&wp[(size_t)dd * ATT]), acc);
        wahp[q][a] = acc;
    }
    __syncthreads();
    if (tid < ATT)
        wahs[tid] = Wa_b[tid] + wahp[0][tid] + wahp[1][tid] + wahp[2][tid] + wahp[3][tid];
    __syncthreads();

    // ---- scores from LDS: 16 waves, local pl stride-16; lane covers 4 a's ----
    {
        int w = tid >> 6, lane = tid & 63;
        float4 wv = *(const float4*)&wahs[lane * 4];
        float4 vv = *(const float4*)&va_w[lane * 4];
        float vb = va_b[0];
        for (int pl = w; pl < cnt; pl += 16) {
            s4v u4 = *(const s4v*)&ufs[pl][lane * 4];
            float ssc = vv.x * tanhf_fast(bf2f(u4.x) + wv.x)
                      + vv.y * tanhf_fast(bf2f(u4.y) + wv.y)
                      + vv.z * tanhf_fast(bf2f(u4.z) + wv.z)
                      + vv.w * tanhf_fast(bf2f(u4.w) + wv.w);
#pragma unroll
            for (int off = 32; off; off >>= 1) ssc += __shfl_down(ssc, off);
            if (lane == 0) sc[pl] = ssc + vb;
        }
    }
    __syncthreads();

    // ---- local softmax over cnt ----
    {
        int lane = tid & 63;
        float v = (tid < cnt) ? sc[tid] : -1e30f;
        if (tid < 128) {
            float m = v;
#pragma unroll
            for (int off = 32; off; off >>= 1) m = fmaxf(m, __shfl_down(m, off));
            if (lane == 0) red[tid >> 6] = m;
        }
        __syncthreads();
        float mh = fmaxf(red[0], red[1]);
        float e = (tid < cnt) ? __expf(v - mh) : 0.f;
        if (tid < 128) {
            float l = e;
#pragma unroll
            for (int off = 32; off; off >>= 1) l += __shfl_down(l, off);
            if (lane == 0) red[2 + (tid >> 6)] = l;
        }
        __syncthreads();
        if (tid < cnt) sc[tid] = e;
        else if (tid < 104) sc[tid] = 0.f;
        if (tid == 0) {
            mlp[((size_t)half * B + b) * 2 + 0] = mh;
            mlp[((size_t)half * B + b) * 2 + 1] = red[2] + red[3];
        }
    }
    __syncthreads();

    // ---- partial (unnormalized) context: (e, ph) split over p-chunks ----
    {
        int e = tid & 511, ph = tid >> 9;
        int start = half ? (ph ? 7 : 0) : (ph ? 6 : 0);
        int nch   = half ? (ph ? 6 : 7) : 6;
        float acc = 0.f;
        const __hip_bfloat16* fr = featT + ((size_t)b * ENC + e) * PP + base + start * 8;
        for (int ch = 0; ch < nch; ++ch) {
            s8v raw = *(const s8v*)(fr + ch * 8);
            const float* sp = &sc[(start + ch) * 8];
#pragma unroll
            for (int j = 0; j < 8; ++j)
                acc = fmaf(sp[j], bf2f(raw[j]), acc);
        }
        cpart[ph][e] = acc;
    }
    __syncthreads();
    if (tid < ENC)
        ctxp[((size_t)half * B + b) * ENC + tid] = cpart[0][tid] + cpart[1][tid];
}

// ---------------- gates partial GEMM: LDS double-buffer, 1 barrier/chunk ----------------
// grid (32 n-tiles, KS=16) = 512 blocks x 256 thr
__global__ __launch_bounds__(256) void k_gates(const float* __restrict__ emb,
        const int* __restrict__ captions, int t,
        const float* __restrict__ ctxp, const float* __restrict__ mlp,
        const float* __restrict__ h,
        const float* __restrict__ W_ih, const float* __restrict__ W_hh,
        float* __restrict__ partials, int use_gemb) {
    __shared__ float As[2][16][128];
    __shared__ float Bs[2][16][64];
    __shared__ float sw0[B], sw1[B];
    __shared__ int scap[B];
    int n0 = blockIdx.x * 64;
    int ks = blockIdx.y;
    int tid = threadIdx.x;
    int kch = use_gemb ? 64 : 80;
    if (tid < B) {
        float m0 = mlp[(size_t)tid * 2 + 0];
        float l0 = mlp[(size_t)tid * 2 + 1];
        float m1 = mlp[((size_t)B + tid) * 2 + 0];
        float l1 = mlp[((size_t)B + tid) * 2 + 1];
        float M = fmaxf(m0, m1);
        float e0 = __expf(m0 - M), e1 = __expf(m1 - M);
        float inv = 1.f / (l0 * e0 + l1 * e1);
        sw0[tid] = e0 * inv; sw1[tid] = e1 * inv;
        if (!use_gemb) scap[tid] = captions[(size_t)tid * S1 + t];
    }
    int tx = tid & 15, ty = tid >> 4;
    float acc[8][4];
#pragma unroll
    for (int i = 0; i < 8; ++i)
#pragma unroll
        for (int j = 0; j < 4; ++j) acc[i][j] = 0.f;
    int arow = tid >> 1, ak = (tid & 1) * 8;
    int bkk = tid >> 4, bn = (tid & 15) * 4;
    int kbase = ks * kch;
    int nch = kch >> 4;
    float rA[8];
    float4 rB;
    __syncthreads();   // sw0/sw1/scap ready (needed by first A load)

    // load chunk 0 into regs
    {
        int k = kbase + ak;
        if (!use_gemb && k < EMB) {
            const float* ap = emb + (size_t)scap[arow] * EMB + k;
            float4 v0 = *(const float4*)ap;
            float4 v1 = *(const float4*)(ap + 4);
            rA[0] = v0.x; rA[1] = v0.y; rA[2] = v0.z; rA[3] = v0.w;
            rA[4] = v1.x; rA[5] = v1.y; rA[6] = v1.z; rA[7] = v1.w;
        } else {
            int kc = use_gemb ? k : (k - EMB);
            if (kc < ENC) {
                const float* p0 = ctxp + (size_t)arow * ENC + kc;
                const float* p1 = ctxp + ((size_t)B + arow) * ENC + kc;
                float w0 = sw0[arow], w1 = sw1[arow];
                float4 a0 = *(const float4*)p0;
                float4 a1 = *(const float4*)(p0 + 4);
                float4 b0 = *(const float4*)p1;
                float4 b1 = *(const float4*)(p1 + 4);
                rA[0] = a0.x * w0 + b0.x * w1; rA[1] = a0.y * w0 + b0.y * w1;
                rA[2] = a0.z * w0 + b0.z * w1; rA[3] = a0.w * w0 + b0.w * w1;
                rA[4] = a1.x * w0 + b1.x * w1; rA[5] = a1.y * w0 + b1.y * w1;
                rA[6] = a1.z * w0 + b1.z * w1; rA[7] = a1.w * w0 + b1.w * w1;
            } else {
                const float* ap = h + (size_t)arow * DEC + (kc - ENC);
                float4 v0 = *(const float4*)ap;
                float4 v1 = *(const float4*)(ap + 4);
                rA[0] = v0.x; rA[1] = v0.y; rA[2] = v0.z; rA[3] = v0.w;
                rA[4] = v1.x; rA[5] = v1.y; rA[6] = v1.z; rA[7] = v1.w;
            }
        }
        int kb = kbase + bkk;
        const float* bp;
        if (use_gemb)
            bp = (kb < ENC) ? W_ih + (size_t)(kb + EMB) * NG + n0 + bn
                            : W_hh + (size_t)(kb - ENC) * NG + n0 + bn;
        else
            bp = (kb < EMB + ENC) ? W_ih + (size_t)kb * NG + n0 + bn
                                  : W_hh + (size_t)(kb - EMB - ENC) * NG + n0 + bn;
        rB = *(const float4*)bp;
    }
#pragma unroll
    for (int i = 0; i < 8; ++i) As[0][ak + i][arow] = rA[i];
    *(float4*)&Bs[0][bkk][bn] = rB;
    __syncthreads();

    for (int c = 0; c < nch; ++c) {
        int cur = c & 1;
        bool more = (c + 1 < nch);
        if (more) {   // prefetch chunk c+1 into regs (overlaps FMA below)
            int k0 = kbase + (c + 1) * 16;
            int k = k0 + ak;
            if (!use_gemb && k < EMB) {
                const float* ap = emb + (size_t)scap[arow] * EMB + k;
                float4 v0 = *(const float4*)ap;
                float4 v1 = *(const float4*)(ap + 4);
                rA[0] = v0.x; rA[1] = v0.y; rA[2] = v0.z; rA[3] = v0.w;
                rA[4] = v1.x; rA[5] = v1.y; rA[6] = v1.z; rA[7] = v1.w;
            } else {
                int kc = use_gemb ? k : (k - EMB);
                if (kc < ENC) {
                    const float* p0 = ctxp + (size_t)arow * ENC + kc;
                    const float* p1 = ctxp + ((size_t)B + arow) * ENC + kc;
                    float w0 = sw0[arow], w1 = sw1[arow];
                    float4 a0 = *(const float4*)p0;
                    float4 a1 = *(const float4*)(p0 + 4);
                    float4 b0 = *(const float4*)p1;
                    float4 b1 = *(const float4*)(p1 + 4);
                    rA[0] = a0.x * w0 + b0.x * w1; rA[1] = a0.y * w0 + b0.y * w1;
                    rA[2] = a0.z * w0 + b0.z * w1; rA[3] = a0.w * w0 + b0.w * w1;
                    rA[4] = a1.x * w0 + b1.x * w1; rA[5] = a1.y * w0 + b1.y * w1;
                    rA[6] = a1.z * w0 + b1.z * w1; rA[7] = a1.w * w0 + b1.w * w1;
                } else {
                    const float* ap = h + (size_t)arow * DEC + (kc - ENC);
                    float4 v0 = *(const float4*)ap;
                    float4 v1 = *(const float4*)(ap + 4);
                    rA[0] = v0.x; rA[1] = v0.y; rA[2] = v0.z; rA[3] = v0.w;
                    rA[4] = v1.x; rA[5] = v1.y; rA[6] = v1.z; rA[7] = v1.w;
                }
            }
            int kb = k0 + bkk;
            const float* bp;
            if (use_gemb)
                bp = (kb < ENC) ? W_ih + (size_t)(kb + EMB) * NG + n0 + bn
                                : W_hh + (size_t)(kb - ENC) * NG + n0 + bn;
            else
                bp = (kb < EMB + ENC) ? W_ih + (size_t)kb * NG + n0 + bn
                                      : W_hh + (size_t)(kb - EMB - ENC) * NG + n0 + bn;
            rB = *(const float4*)bp;
        }
#pragma unroll
        for (int kk = 0; kk < 16; ++kk) {
            float4 a0 = *(const float4*)&As[cur][kk][ty * 8];
            float4 a1 = *(const float4*)&As[cur][kk][ty * 8 + 4];
            float4 b0 = *(const float4*)&Bs[cur][kk][tx * 4];
            float av[8] = {a0.x, a0.y, a0.z, a0.w, a1.x, a1.y, a1.z, a1.w};
            float bv[4] = {b0.x, b0.y, b0.z, b0.w};
#pragma unroll
            for (int i = 0; i < 8; ++i)
#pragma unroll
                for (int j = 0; j < 4; ++j)
                    acc[i][j] = fmaf(av[i], bv[j], acc[i][j]);
        }
        if (more) {
#pragma unroll
            for (int i = 0; i < 8; ++i) As[cur ^ 1][ak + i][arow] = rA[i];
            *(float4*)&Bs[cur ^ 1][bkk][bn] = rB;
            __syncthreads();
        }
    }
#pragma unroll
    for (int i = 0; i < 8; ++i) {
        int mrow = ty * 8 + i;
        float* pp = partials + ((size_t)ks * B + mrow) * NG + n0 + tx * 4;
        *(float4*)pp = make_float4(acc[i][0], acc[i][1], acc[i][2], acc[i][3]);
    }
}

// ---------------- output projection GEMM ----------------
__global__ __launch_bounds__(256) void k_fcn(const float* __restrict__ A,
        const float* __restrict__ Bw, const float* __restrict__ bias,
        float* __restrict__ out, int t_fix) {
    __shared__ float As[16][128];
    __shared__ float Bs[16][128];
    int m0 = blockIdx.x * 128;
    int n0 = blockIdx.y * 128;
    int tid = threadIdx.x;
    int tx = tid & 15, ty = tid >> 4;
    float acc[8][8];
#pragma unroll
    for (int i = 0; i < 8; ++i)
#pragma unroll
        for (int j = 0; j < 8; ++j) acc[i][j] = 0.f;
    int arow = tid >> 1, ak = (tid & 1) * 8;
    int bkk = tid >> 4, bn = (tid & 15) * 8;
    const float4 z4 = make_float4(0.f, 0.f, 0.f, 0.f);
    for (int k0 = 0; k0 < DEC; k0 += 16) {
        {
            const float* ap = A + (size_t)(m0 + arow) * DEC + k0 + ak;
            float4 v0 = *(const float4*)ap;
            float4 v1 = *(const float4*)(ap + 4);
            As[ak + 0][arow] = v0.x; As[ak + 1][arow] = v0.y;
            As[ak + 2][arow] = v0.z; As[ak + 3][arow] = v0.w;
            As[ak + 4][arow] = v1.x; As[ak + 5][arow] = v1.y;
            As[ak + 6][arow] = v1.z; As[ak + 7][arow] = v1.w;
        }
        {
            int n4 = n0 + bn;
            const float* bp = Bw + (size_t)(k0 + bkk) * V + n4;
            float4 v0 = (n4 < V) ? *(const float4*)bp : z4;
            float4 v1 = (n4 + 4 < V) ? *(const float4*)(bp + 4) : z4;
            *(float4*)&Bs[bkk][bn] = v0;
            *(float4*)&Bs[bkk][bn + 4] = v1;
        }
        __syncthreads();
#pragma unroll
        for (int kk = 0; kk < 16; ++kk) {
            float4 a0 = *(const float4*)&As[kk][ty * 8];
            float4 a1 = *(const float4*)&As[kk][ty * 8 + 4];
            float4 b0 = *(const float4*)&Bs[kk][tx * 8];
            float4 b1 = *(const float4*)&Bs[kk][tx * 8 + 4];
            float av[8] = {a0.x, a0.y, a0.z, a0.w, a1.x, a1.y, a1.z, a1.w};
            float bv[8] = {b0.x, b0.y, b0.z, b0.w, b1.x, b1.y, b1.z, b1.w};
#pragma unroll
            for (int i = 0; i < 8; ++i)
#pragma unroll
                for (int j = 0; j < 8; ++j)
                    acc[i][j] = fmaf(av[i], bv[j], acc[i][j]);
        }
        __syncthreads();
    }
#pragma unroll
    for (int i = 0; i < 8; ++i) {
        int mrow = m0 + ty * 8 + i;
        int bb, tt;
        if (t_fix >= 0) { bb = mrow; tt = t_fix; }
        else            { tt = mrow >> 7; bb = mrow & 127; }
        float* op = out + ((size_t)bb * S + tt) * V + n0 + tx * 8;
#pragma unroll
        for (int j = 0; j < 8; ++j) {
            int n = n0 + tx * 8 + j;
            if (n < V) op[j] = acc[i][j] + bias[n];
        }
    }
}

extern "C" void kernel_launch(void* const* d_in, const int* in_sizes, int n_in,
                              void* d_out, int out_size, void* d_ws, size_t ws_size,
                              hipStream_t stream) {
    const float* features = (const float*)d_in[0];
    const int*   captions = (const int*)d_in[1];
    const float* emb      = (const float*)d_in[2];
    const float* Ua_w     = (const float*)d_in[3];
    const float* Ua_b     = (const float*)d_in[4];
    const float* Wa_w     = (const float*)d_in[5];
    const float* Wa_b     = (const float*)d_in[6];
    const float* va_w     = (const float*)d_in[7];
    const float* va_b     = (const float*)d_in[8];
    const float* ih_w     = (const float*)d_in[9];
    const float* ih_b     = (const float*)d_in[10];
    const float* ic_w     = (const float*)d_in[11];
    const float* ic_b     = (const float*)d_in[12];
    const float* W_ih     = (const float*)d_in[13];
    const float* b_ih     = (const float*)d_in[14];
    const float* W_hh     = (const float*)d_in[15];
    const float* b_hh     = (const float*)d_in[16];
    const float* fcn_w    = (const float*)d_in[17];
    const float* fcn_b    = (const float*)d_in[18];
    float* out = (float*)d_out;
    char* wsb  = (char*)d_ws;

    size_t off = 0;
    __hip_bfloat16* Uf    = (__hip_bfloat16*)(wsb + off); off += (size_t)B * P * ATT * 2;    // 12.8MB
    __hip_bfloat16* featT = (__hip_bfloat16*)(wsb + off); off += (size_t)B * ENC * PP * 2;   // 26.2MB
    __hip_bfloat16* Wa_wb = (__hip_bfloat16*)(wsb + off); off += (size_t)DEC * ATT * 2;
    float* partials = (float*)(wsb + off); off += (size_t)KS * B * NG * 4;                   // 16.8MB
    float* hbuf     = (float*)(wsb + off); off += (size_t)B * DEC * 4;
    float* cbufA    = (float*)(wsb + off); off += (size_t)B * DEC * 4;
    float* cbufB    = (float*)(wsb + off); off += (size_t)B * DEC * 4;
    float* ctxp     = (float*)(wsb + off); off += (size_t)2 * B * ENC * 4;
    float* mlp      = (float*)(wsb + off); off += 4096;
    float* meanf    = ctxp;   // alias: meanf used only before ctxp's first use
    size_t need_min = off;
    float* Hall     = (float*)(wsb + off); off += (size_t)S * B * DEC * 4;                   // 67MB
    size_t need_hall = off;
    __hip_bfloat16* Gemb = (__hip_bfloat16*)(wsb + off);
    off += (size_t)S * B * NG * 2;                                                           // 134MB
    size_t need_gemb = off;

    (void)need_min;
    int use_hall = ws_size >= need_hall;
    int use_gemb = ws_size >= need_gemb;

    k_mean<<<256, 256, 0, stream>>>(features, meanf);
    k_init_hc<<<256, 256, 0, stream>>>(meanf, ih_w, ih_b, ic_w, ic_b, hbuf, cbufA);
    k_uf<<<3136, 256, 0, stream>>>(features, Ua_w, Ua_b, Uf);
    k_featT<<<dim3(128, 25), 512, 0, stream>>>(features, featT);
    k_wacvt<<<512, 256, 0, stream>>>(Wa_w, Wa_wb);
    if (use_gemb)
        k_gemb<<<dim3(256, 16), 256, 0, stream>>>(emb, captions, W_ih, Gemb);

    for (int t = 0; t <= S; ++t) {
        const float* crd = (t & 1) ? cbufA : cbufB;
        float*       cwr = (t & 1) ? cbufB : cbufA;
        k_attn_cell<<<256, 1024, 0, stream>>>(partials, Gemb, b_ih, b_hh,
                hbuf, crd, cwr, Hall, Wa_wb, Wa_b, Uf, featT, va_w, va_b,
                ctxp, mlp, t, use_gemb, use_hall);
        if (t < S)
            k_gates<<<dim3(32, KS), 256, 0, stream>>>(emb, captions, t, ctxp, mlp,
                    hbuf, W_ih, W_hh, partials, use_gemb);
        if (!use_hall && t > 0)
            k_fcn<<<dim3(1, 40), 256, 0, stream>>>(hbuf, fcn_w, fcn_b, out, t - 1);
    }
    if (use_hall)
        k_fcn<<<dim3(256, 40), 256, 0, stream>>>(Hall, fcn_w, fcn_b, out, -1);
}

// Round 9
// 13032.056 us; speedup vs baseline: 1.3366x; 1.0825x over previous
//
#include <hip/hip_runtime.h>
#include <hip/hip_bf16.h>

#define B 128
#define P 196
#define PP 200       // padded P (bf16 rows 400B, 16B-aligned)
#define ENC 512
#define DEC 512
#define ATT 256
#define EMB 256
#define V 5000
#define NP 5120      // V padded to 128-multiple for MFMA fcn
#define S 256
#define S1 257
#define NG 2048      // 4*DEC
#define KS 16        // k-splits for gates GEMM
#define KTP 40       // LDS K-pitch for MFMA tiles (32 + 8 pad)

typedef __attribute__((ext_vector_type(4))) short s4v;
typedef __attribute__((ext_vector_type(8))) short s8v;
typedef __attribute__((ext_vector_type(4))) float f32x4;

__device__ __forceinline__ float bf2f(short u) {
    unsigned int x = ((unsigned int)(unsigned short)u) << 16;
    float f; __builtin_memcpy(&f, &x, 4); return f;
}

// fast tanh: (e^2x - 1) / (e^2x + 1), clamp to avoid inf/inf
__device__ __forceinline__ float tanhf_fast(float x) {
    float xx = fminf(fmaxf(x, -15.f), 15.f);
    float t = __expf(2.f * xx);
    return (t - 1.f) * __builtin_amdgcn_rcpf(t + 1.f);
}

// ---------------- mean over P ----------------
__global__ __launch_bounds__(256) void k_mean(const float* __restrict__ feat,
                                              float* __restrict__ mean_f) {
    int idx = blockIdx.x * 256 + threadIdx.x;
    int b = idx >> 9, e = idx & 511;
    const float* fp = feat + (size_t)b * P * ENC + e;
    float s = 0.f;
    for (int p = 0; p < P; ++p) s += fp[(size_t)p * ENC];
    mean_f[idx] = s * (1.0f / (float)P);
}

// ---------------- h0 / c0 ----------------
__global__ __launch_bounds__(256) void k_init_hc(const float* __restrict__ mean_f,
        const float* __restrict__ ih_w, const float* __restrict__ ih_b,
        const float* __restrict__ ic_w, const float* __restrict__ ic_b,
        float* __restrict__ h, float* __restrict__ c) {
    int idx = blockIdx.x * 256 + threadIdx.x;
    int b = idx >> 9, d = idx & 511;
    const float* mf = mean_f + (size_t)b * ENC;
    float sh = ih_b[d], sc = ic_b[d];
    for (int e = 0; e < ENC; ++e) {
        float m = mf[e];
        sh = fmaf(m, ih_w[(size_t)e * DEC + d], sh);
        sc = fmaf(m, ic_w[(size_t)e * DEC + d], sc);
    }
    h[idx] = sh; c[idx] = sc;
}

// ---------------- Uf = features @ Ua_w + Ua_b  (bf16 out) ----------------
__global__ __launch_bounds__(256) void k_uf(const float* __restrict__ feat,
        const float* __restrict__ Ua_w, const float* __restrict__ Ua_b,
        __hip_bfloat16* __restrict__ Uf) {
    int row0 = blockIdx.x * 8;
    int a = threadIdx.x;
    __shared__ float fs[8][ENC];
    for (int i = threadIdx.x; i < 8 * ENC; i += 256) {
        int r = i >> 9, e = i & 511;
        fs[r][e] = feat[(size_t)(row0 + r) * ENC + e];
    }
    __syncthreads();
    float acc[8];
    float bia = Ua_b[a];
#pragma unroll
    for (int r = 0; r < 8; ++r) acc[r] = bia;
    for (int e = 0; e < ENC; ++e) {
        float w = Ua_w[(size_t)e * ATT + a];
#pragma unroll
        for (int r = 0; r < 8; ++r) acc[r] = fmaf(fs[r][e], w, acc[r]);
    }
#pragma unroll
    for (int r = 0; r < 8; ++r)
        Uf[(size_t)(row0 + r) * ATT + a] = __float2bfloat16(acc[r]);
}

// ---------------- featT[b][e][p] bf16, zero-padded to PP ----------------
__global__ __launch_bounds__(512) void k_featT(const float* __restrict__ feat,
        __hip_bfloat16* __restrict__ featT) {
    int b = blockIdx.x, p0 = blockIdx.y * 8;
    int e = threadIdx.x;
    __hip_bfloat16 v[8];
#pragma unroll
    for (int i = 0; i < 8; ++i) {
        int p = p0 + i;
        float f = (p < P) ? feat[((size_t)b * P + p) * ENC + e] : 0.f;
        v[i] = __float2bfloat16(f);
    }
    __builtin_memcpy(&featT[((size_t)b * ENC + e) * PP + p0], v, 16);
}

// ---------------- Wa_w -> bf16 transposed: WaT[a][d] ----------------
__global__ __launch_bounds__(256) void k_watr(const float* __restrict__ w,
        __hip_bfloat16* __restrict__ wT) {
    int i = blockIdx.x * 256 + threadIdx.x;   // over DEC*ATT, i = d*ATT + a
    int d = i >> 8, a = i & 255;
    wT[(size_t)a * DEC + d] = __float2bfloat16(w[i]);
}

// ---------------- Gemb = embeds[:, :S] @ W_ih[:EMB]  (bf16 out) ----------------
__global__ __launch_bounds__(256) void k_gemb(const float* __restrict__ emb,
        const int* __restrict__ captions, const float* __restrict__ W_ih,
        __hip_bfloat16* __restrict__ Gemb) {
    __shared__ float As[16][128];
    __shared__ float Bs[16][128];
    __shared__ int rowcap[128];
    int m0 = blockIdx.x * 128;
    int n0 = blockIdx.y * 128;
    int tid = threadIdx.x;
    if (tid < 128) {
        int m = m0 + tid;
        rowcap[tid] = captions[(size_t)(m & 127) * S1 + (m >> 7)];
    }
    __syncthreads();
    int tx = tid & 15, ty = tid >> 4;
    float acc[8][8];
#pragma unroll
    for (int i = 0; i < 8; ++i)
#pragma unroll
        for (int j = 0; j < 8; ++j) acc[i][j] = 0.f;
    int arow = tid >> 1, ak = (tid & 1) * 8;
    int bkk = tid >> 4, bn = (tid & 15) * 8;
    for (int k0 = 0; k0 < EMB; k0 += 16) {
        {
            const float* ap = emb + (size_t)rowcap[arow] * EMB + k0 + ak;
            float4 v0 = *(const float4*)ap;
            float4 v1 = *(const float4*)(ap + 4);
            As[ak + 0][arow] = v0.x; As[ak + 1][arow] = v0.y;
            As[ak + 2][arow] = v0.z; As[ak + 3][arow] = v0.w;
            As[ak + 4][arow] = v1.x; As[ak + 5][arow] = v1.y;
            As[ak + 6][arow] = v1.z; As[ak + 7][arow] = v1.w;
        }
        {
            const float* bp = W_ih + (size_t)(k0 + bkk) * NG + n0 + bn;
            *(float4*)&Bs[bkk][bn] = *(const float4*)bp;
            *(float4*)&Bs[bkk][bn + 4] = *(const float4*)(bp + 4);
        }
        __syncthreads();
#pragma unroll
        for (int kk = 0; kk < 16; ++kk) {
            float4 a0 = *(const float4*)&As[kk][ty * 8];
            float4 a1 = *(const float4*)&As[kk][ty * 8 + 4];
            float4 b0 = *(const float4*)&Bs[kk][tx * 8];
            float4 b1 = *(const float4*)&Bs[kk][tx * 8 + 4];
            float av[8] = {a0.x, a0.y, a0.z, a0.w, a1.x, a1.y, a1.z, a1.w};
            float bv[8] = {b0.x, b0.y, b0.z, b0.w, b1.x, b1.y, b1.z, b1.w};
#pragma unroll
            for (int i = 0; i < 8; ++i)
#pragma unroll
                for (int j = 0; j < 8; ++j)
                    acc[i][j] = fmaf(av[i], bv[j], acc[i][j]);
        }
        __syncthreads();
    }
#pragma unroll
    for (int i = 0; i < 8; ++i) {
        __hip_bfloat16* gp = Gemb + (size_t)(m0 + ty * 8 + i) * NG + n0 + tx * 8;
#pragma unroll
        for (int j = 0; j < 8; ++j) gp[j] = __float2bfloat16(acc[i][j]);
    }
}

// ======== fused: cell + wah + half-attention, with Uf LDS prefetch ========
__global__ __launch_bounds__(1024) void k_attn_cell(
        const float* __restrict__ partials, const __hip_bfloat16* __restrict__ Gemb,
        const float* __restrict__ b_ih, const float* __restrict__ b_hh,
        float* __restrict__ h, const float* __restrict__ cr, float* __restrict__ cw,
        __hip_bfloat16* __restrict__ HallH, __hip_bfloat16* __restrict__ HallL,
        const __hip_bfloat16* __restrict__ WaT, const float* __restrict__ Wa_b,
        const __hip_bfloat16* __restrict__ Uf, const __hip_bfloat16* __restrict__ featT,
        const float* __restrict__ va_w, const float* __restrict__ va_b,
        float* __restrict__ ctxp, float* __restrict__ mlp,
        int t, int use_gemb, int use_hall) {
    int g = blockIdx.x;
    int b = g >> 1, half = g & 1;
    int tid = threadIdx.x;
    int base = half ? 96 : 0;
    int cnt  = half ? 100 : 96;    // real positions
    __shared__ short ufs[100][ATT];      // 51.2 KB bf16 Uf slice
    __shared__ float hs[DEC];
    __shared__ float wahp[4][ATT];
    __shared__ float wahs[ATT];
    __shared__ float sc[104];
    __shared__ float red[4];
    __shared__ float cpart[2][ENC];

    // ---- phase 0: cell (tid < 512) || Uf prefetch (tid >= 512) ----
    if (tid < 512) {
        if (t > 0) {
            int d = tid;
            float s0 = b_ih[d]           + b_hh[d];
            float s1 = b_ih[d + DEC]     + b_hh[d + DEC];
            float s2 = b_ih[d + 2 * DEC] + b_hh[d + 2 * DEC];
            float s3 = b_ih[d + 3 * DEC] + b_hh[d + 3 * DEC];
#pragma unroll
            for (int ks = 0; ks < KS; ++ks) {
                const float* pp = partials + ((size_t)ks * B + b) * NG + d;
                s0 += pp[0]; s1 += pp[DEC]; s2 += pp[2 * DEC]; s3 += pp[3 * DEC];
            }
            if (use_gemb) {
                const __hip_bfloat16* gp = Gemb + ((size_t)(t - 1) * B + b) * NG + d;
                s0 += __bfloat162float(gp[0]);
                s1 += __bfloat162float(gp[DEC]);
                s2 += __bfloat162float(gp[2 * DEC]);
                s3 += __bfloat162float(gp[3 * DEC]);
            }
            size_t gidx = (size_t)b * DEC + d;
            float ii = 1.f / (1.f + __expf(-s0));
            float ff = 1.f / (1.f + __expf(-s1));
            float gg = tanhf_fast(s2);
            float oo = 1.f / (1.f + __expf(-s3));
            float cn = ff * cr[gidx] + ii * gg;
            float hn = oo * tanhf_fast(cn);
            hs[d] = hn;
            if (half == 0) {
                cw[gidx] = cn;
                h[gidx] = hn;
                if (use_hall) {
                    __hip_bfloat16 hi = __float2bfloat16(hn);
                    float lo = hn - __bfloat162float(hi);
                    size_t hidx = ((size_t)(t - 1) * B + b) * DEC + d;
                    HallH[hidx] = hi;
                    HallL[hidx] = __float2bfloat16(lo);
                }
            }
        } else {
            hs[tid] = h[(size_t)b * DEC + tid];
        }
    } else if (t < S) {
        // prefetch Uf slice [cnt][256] bf16 into LDS
        const __hip_bfloat16* ub = Uf + ((size_t)b * P + base) * ATT;
        for (int i = tid - 512; i < cnt * 32; i += 512) {
            int p = i >> 5, c = (i & 31) * 8;
            *(s8v*)&ufs[p][c] = *(const s8v*)(ub + (size_t)p * ATT + c);
        }
    }
    __syncthreads();
    if (t == S) return;

    // ---- wah GEMV: thread (a, q) covers d in [q*128, q*128+128), WaT rows ----
    {
        int a = tid & 255, q = tid >> 8;
        const __hip_bfloat16* wp = WaT + (size_t)a * DEC + q * 128;
        float acc = 0.f;
#pragma unroll
        for (int c = 0; c < 16; ++c) {
            s8v w8 = *(const s8v*)(wp + c * 8);
            const float* hq = &hs[q * 128 + c * 8];
#pragma unroll
            for (int j = 0; j < 8; ++j)
                acc = fmaf(hq[j], bf2f(w8[j]), acc);
        }
        wahp[q][a] = acc;
    }
    __syncthreads();
    if (tid < ATT)
        wahs[tid] = Wa_b[tid] + wahp[0][tid] + wahp[1][tid] + wahp[2][tid] + wahp[3][tid];
    __syncthreads();

    // ---- scores from LDS: 16 waves, local pl stride-16; lane covers 4 a's ----
    {
        int w = tid >> 6, lane = tid & 63;
        float4 wv = *(const float4*)&wahs[lane * 4];
        float4 vv = *(const float4*)&va_w[lane * 4];
        float vb = va_b[0];
        for (int pl = w; pl < cnt; pl += 16) {
            s4v u4 = *(const s4v*)&ufs[pl][lane * 4];
            float ssc = vv.x * tanhf_fast(bf2f(u4.x) + wv.x)
                      + vv.y * tanhf_fast(bf2f(u4.y) + wv.y)
                      + vv.z * tanhf_fast(bf2f(u4.z) + wv.z)
                      + vv.w * tanhf_fast(bf2f(u4.w) + wv.w);
#pragma unroll
            for (int off = 32; off; off >>= 1) ssc += __shfl_down(ssc, off);
            if (lane == 0) sc[pl] = ssc + vb;
        }
    }
    __syncthreads();

    // ---- local softmax over cnt ----
    {
        int lane = tid & 63;
        float v = (tid < cnt) ? sc[tid] : -1e30f;
        if (tid < 128) {
            float m = v;
#pragma unroll
            for (int off = 32; off; off >>= 1) m = fmaxf(m, __shfl_down(m, off));
            if (lane == 0) red[tid >> 6] = m;
        }
        __syncthreads();
        float mh = fmaxf(red[0], red[1]);
        float e = (tid < cnt) ? __expf(v - mh) : 0.f;
        if (tid < 128) {
            float l = e;
#pragma unroll
            for (int off = 32; off; off >>= 1) l += __shfl_down(l, off);
            if (lane == 0) red[2 + (tid >> 6)] = l;
        }
        __syncthreads();
        if (tid < cnt) sc[tid] = e;
        else if (tid < 104) sc[tid] = 0.f;
        if (tid == 0) {
            mlp[((size_t)half * B + b) * 2 + 0] = mh;
            mlp[((size_t)half * B + b) * 2 + 1] = red[2] + red[3];
        }
    }
    __syncthreads();

    // ---- partial (unnormalized) context: (e, ph) split over p-chunks ----
    {
        int e = tid & 511, ph = tid >> 9;
        int start = half ? (ph ? 7 : 0) : (ph ? 6 : 0);
        int nch   = half ? (ph ? 6 : 7) : 6;
        float acc = 0.f;
        const __hip_bfloat16* fr = featT + ((size_t)b * ENC + e) * PP + base + start * 8;
        for (int ch = 0; ch < nch; ++ch) {
            s8v raw = *(const s8v*)(fr + ch * 8);
            const float* sp = &sc[(start + ch) * 8];
#pragma unroll
            for (int j = 0; j < 8; ++j)
                acc = fmaf(sp[j], bf2f(raw[j]), acc);
        }
        cpart[ph][e] = acc;
    }
    __syncthreads();
    if (tid < ENC)
        ctxp[((size_t)half * B + b) * ENC + tid] = cpart[0][tid] + cpart[1][tid];
}

// ---------------- gates partial GEMM: LDS double-buffer, 1 barrier/chunk ----------------
__global__ __launch_bounds__(256) void k_gates(const float* __restrict__ emb,
        const int* __restrict__ captions, int t,
        const float* __restrict__ ctxp, const float* __restrict__ mlp,
        const float* __restrict__ h,
        const float* __restrict__ W_ih, const float* __restrict__ W_hh,
        float* __restrict__ partials, int use_gemb) {
    __shared__ float As[2][16][128];
    __shared__ float Bs[2][16][64];
    __shared__ float sw0[B], sw1[B];
    __shared__ int scap[B];
    int n0 = blockIdx.x * 64;
    int ks = blockIdx.y;
    int tid = threadIdx.x;
    int kch = use_gemb ? 64 : 80;
    if (tid < B) {
        float m0 = mlp[(size_t)tid * 2 + 0];
        float l0 = mlp[(size_t)tid * 2 + 1];
        float m1 = mlp[((size_t)B + tid) * 2 + 0];
        float l1 = mlp[((size_t)B + tid) * 2 + 1];
        float M = fmaxf(m0, m1);
        float e0 = __expf(m0 - M), e1 = __expf(m1 - M);
        float inv = 1.f / (l0 * e0 + l1 * e1);
        sw0[tid] = e0 * inv; sw1[tid] = e1 * inv;
        if (!use_gemb) scap[tid] = captions[(size_t)tid * S1 + t];
    }
    int tx = tid & 15, ty = tid >> 4;
    float acc[8][4];
#pragma unroll
    for (int i = 0; i < 8; ++i)
#pragma unroll
        for (int j = 0; j < 4; ++j) acc[i][j] = 0.f;
    int arow = tid >> 1, ak = (tid & 1) * 8;
    int bkk = tid >> 4, bn = (tid & 15) * 4;
    int kbase = ks * kch;
    int nch = kch >> 4;
    float rA[8];
    float4 rB;
    __syncthreads();

    {
        int k = kbase + ak;
        if (!use_gemb && k < EMB) {
            const float* ap = emb + (size_t)scap[arow] * EMB + k;
            float4 v0 = *(const float4*)ap;
            float4 v1 = *(const float4*)(ap + 4);
            rA[0] = v0.x; rA[1] = v0.y; rA[2] = v0.z; rA[3] = v0.w;
            rA[4] = v1.x; rA[5] = v1.y; rA[6] = v1.z; rA[7] = v1.w;
        } else {
            int kc = use_gemb ? k : (k - EMB);
            if (kc < ENC) {
                const float* p0 = ctxp + (size_t)arow * ENC + kc;
                const float* p1 = ctxp + ((size_t)B + arow) * ENC + kc;
                float w0 = sw0[arow], w1 = sw1[arow];
                float4 a0 = *(const float4*)p0;
                float4 a1 = *(const float4*)(p0 + 4);
                float4 b0 = *(const float4*)p1;
                float4 b1 = *(const float4*)(p1 + 4);
                rA[0] = a0.x * w0 + b0.x * w1; rA[1] = a0.y * w0 + b0.y * w1;
                rA[2] = a0.z * w0 + b0.z * w1; rA[3] = a0.w * w0 + b0.w * w1;
                rA[4] = a1.x * w0 + b1.x * w1; rA[5] = a1.y * w0 + b1.y * w1;
                rA[6] = a1.z * w0 + b1.z * w1; rA[7] = a1.w * w0 + b1.w * w1;
            } else {
                const float* ap = h + (size_t)arow * DEC + (kc - ENC);
                float4 v0 = *(const float4*)ap;
                float4 v1 = *(const float4*)(ap + 4);
                rA[0] = v0.x; rA[1] = v0.y; rA[2] = v0.z; rA[3] = v0.w;
                rA[4] = v1.x; rA[5] = v1.y; rA[6] = v1.z; rA[7] = v1.w;
            }
        }
        int kb = kbase + bkk;
        const float* bp;
        if (use_gemb)
            bp = (kb < ENC) ? W_ih + (size_t)(kb + EMB) * NG + n0 + bn
                            : W_hh + (size_t)(kb - ENC) * NG + n0 + bn;
        else
            bp = (kb < EMB + ENC) ? W_ih + (size_t)kb * NG + n0 + bn
                                  : W_hh + (size_t)(kb - EMB - ENC) * NG + n0 + bn;
        rB = *(const float4*)bp;
    }
#pragma unroll
    for (int i = 0; i < 8; ++i) As[0][ak + i][arow] = rA[i];
    *(float4*)&Bs[0][bkk][bn] = rB;
    __syncthreads();

    for (int c = 0; c < nch; ++c) {
        int cur = c & 1;
        bool more = (c + 1 < nch);
        if (more) {
            int k0 = kbase + (c + 1) * 16;
            int k = k0 + ak;
            if (!use_gemb && k < EMB) {
                const float* ap = emb + (size_t)scap[arow] * EMB + k;
                float4 v0 = *(const float4*)ap;
                float4 v1 = *(const float4*)(ap + 4);
                rA[0] = v0.x; rA[1] = v0.y; rA[2] = v0.z; rA[3] = v0.w;
                rA[4] = v1.x; rA[5] = v1.y; rA[6] = v1.z; rA[7] = v1.w;
            } else {
                int kc = use_gemb ? k : (k - EMB);
                if (kc < ENC) {
                    const float* p0 = ctxp + (size_t)arow * ENC + kc;
                    const float* p1 = ctxp + ((size_t)B + arow) * ENC + kc;
                    float w0 = sw0[arow], w1 = sw1[arow];
                    float4 a0 = *(const float4*)p0;
                    float4 a1 = *(const float4*)(p0 + 4);
                    float4 b0 = *(const float4*)p1;
                    float4 b1 = *(const float4*)(p1 + 4);
                    rA[0] = a0.x * w0 + b0.x * w1; rA[1] = a0.y * w0 + b0.y * w1;
                    rA[2] = a0.z * w0 + b0.z * w1; rA[3] = a0.w * w0 + b0.w * w1;
                    rA[4] = a1.x * w0 + b1.x * w1; rA[5] = a1.y * w0 + b1.y * w1;
                    rA[6] = a1.z * w0 + b1.z * w1; rA[7] = a1.w * w0 + b1.w * w1;
                } else {
                    const float* ap = h + (size_t)arow * DEC + (kc - ENC);
                    float4 v0 = *(const float4*)ap;
                    float4 v1 = *(const float4*)(ap + 4);
                    rA[0] = v0.x; rA[1] = v0.y; rA[2] = v0.z; rA[3] = v0.w;
                    rA[4] = v1.x; rA[5] = v1.y; rA[6] = v1.z; rA[7] = v1.w;
                }
            }
            int kb = k0 + bkk;
            const float* bp;
            if (use_gemb)
                bp = (kb < ENC) ? W_ih + (size_t)(kb + EMB) * NG + n0 + bn
                                : W_hh + (size_t)(kb - ENC) * NG + n0 + bn;
            else
                bp = (kb < EMB + ENC) ? W_ih + (size_t)kb * NG + n0 + bn
                                      : W_hh + (size_t)(kb - EMB - ENC) * NG + n0 + bn;
            rB = *(const float4*)bp;
        }
#pragma unroll
        for (int kk = 0; kk < 16; ++kk) {
            float4 a0 = *(const float4*)&As[cur][kk][ty * 8];
            float4 a1 = *(const float4*)&As[cur][kk][ty * 8 + 4];
            float4 b0 = *(const float4*)&Bs[cur][kk][tx * 4];
            float av[8] = {a0.x, a0.y, a0.z, a0.w, a1.x, a1.y, a1.z, a1.w};
            float bv[4] = {b0.x, b0.y, b0.z, b0.w};
#pragma unroll
            for (int i = 0; i < 8; ++i)
#pragma unroll
                for (int j = 0; j < 4; ++j)
                    acc[i][j] = fmaf(av[i], bv[j], acc[i][j]);
        }
        if (more) {
#pragma unroll
            for (int i = 0; i < 8; ++i) As[cur ^ 1][ak + i][arow] = rA[i];
            *(float4*)&Bs[cur ^ 1][bkk][bn] = rB;
            __syncthreads();
        }
    }
#pragma unroll
    for (int i = 0; i < 8; ++i) {
        int mrow = ty * 8 + i;
        float* pp = partials + ((size_t)ks * B + mrow) * NG + n0 + tx * 4;
        *(float4*)pp = make_float4(acc[i][0], acc[i][1], acc[i][2], acc[i][3]);
    }
}

// ---------------- fcn_w -> hi/lo bf16, transposed + padded: W*T[n][k] ----------------
__global__ __launch_bounds__(256) void k_wsplit(const float* __restrict__ w,
        __hip_bfloat16* __restrict__ WhiT, __hip_bfloat16* __restrict__ WloT) {
    __shared__ float ls[32][65];
    int k0 = blockIdx.x * 32;
    int n0 = blockIdx.y * 64;
    int tid = threadIdx.x;
    for (int idx = tid; idx < 32 * 64; idx += 256) {
        int kk = idx >> 6, nn = idx & 63;
        int n = n0 + nn;
        ls[kk][nn] = (n < V) ? w[(size_t)(k0 + kk) * V + n] : 0.f;
    }
    __syncthreads();
    for (int idx = tid; idx < 64 * 32; idx += 256) {
        int nn = idx >> 5, kk = idx & 31;
        float x = ls[kk][nn];
        __hip_bfloat16 hi = __float2bfloat16(x);
        float lo = x - __bfloat162float(hi);
        size_t o = (size_t)(n0 + nn) * 512 + k0 + kk;
        WhiT[o] = hi;
        WloT[o] = __float2bfloat16(lo);
    }
}

// ---------------- MFMA output projection: split-bf16, 3 products ----------------
// grid (256 m-tiles, 40 n-tiles), 256 thr (4 waves, each 64x64).
__global__ __launch_bounds__(256) void k_fcn_mfma(
        const __hip_bfloat16* __restrict__ Ahi, const __hip_bfloat16* __restrict__ Alo,
        const __hip_bfloat16* __restrict__ WhiT, const __hip_bfloat16* __restrict__ WloT,
        const float* __restrict__ bias, float* __restrict__ out) {
    __shared__ short AsH[128][KTP], AsL[128][KTP];
    __shared__ short BsH[128][KTP], BsL[128][KTP];
    int m0 = blockIdx.x * 128;
    int n0 = blockIdx.y * 128;
    int tid = threadIdx.x;
    int wid = tid >> 6, lane = tid & 63;
    int wr = wid >> 1, wc = wid & 1;
    f32x4 acc[4][4] = {};
    int r = tid & 127;
    const __hip_bfloat16* asrc = (tid < 128 ? Ahi : Alo) + (size_t)(m0 + r) * 512;
    const __hip_bfloat16* bsrc = (tid < 128 ? WhiT : WloT) + (size_t)(n0 + r) * 512;
    short* adst = (tid < 128 ? &AsH[r][0] : &AsL[r][0]);
    short* bdst = (tid < 128 ? &BsH[r][0] : &BsL[r][0]);
    int l15 = lane & 15, kof = (lane >> 4) * 8;

    for (int k0 = 0; k0 < 512; k0 += 32) {
        // stage A and B tiles (hi by threads<128, lo by threads>=128)
        {
            const __hip_bfloat16* s = asrc + k0;
            *(s8v*)(adst + 0)  = *(const s8v*)(s + 0);
            *(s8v*)(adst + 8)  = *(const s8v*)(s + 8);
            *(s8v*)(adst + 16) = *(const s8v*)(s + 16);
            *(s8v*)(adst + 24) = *(const s8v*)(s + 24);
            const __hip_bfloat16* sb = bsrc + k0;
            *(s8v*)(bdst + 0)  = *(const s8v*)(sb + 0);
            *(s8v*)(bdst + 8)  = *(const s8v*)(sb + 8);
            *(s8v*)(bdst + 16) = *(const s8v*)(sb + 16);
            *(s8v*)(bdst + 24) = *(const s8v*)(sb + 24);
        }
        __syncthreads();
        s8v ah[4], al[4], bh[4], bl[4];
#pragma unroll
        for (int mi = 0; mi < 4; ++mi) {
            int row = wr * 64 + mi * 16 + l15;
            ah[mi] = *(const s8v*)&AsH[row][kof];
            al[mi] = *(const s8v*)&AsL[row][kof];
        }
#pragma unroll
        for (int ni = 0; ni < 4; ++ni) {
            int row = wc * 64 + ni * 16 + l15;
            bh[ni] = *(const s8v*)&BsH[row][kof];
            bl[ni] = *(const s8v*)&BsL[row][kof];
        }
#pragma unroll
        for (int mi = 0; mi < 4; ++mi)
#pragma unroll
            for (int ni = 0; ni < 4; ++ni) {
                acc[mi][ni] = __builtin_amdgcn_mfma_f32_16x16x32_bf16(ah[mi], bh[ni], acc[mi][ni], 0, 0, 0);
                acc[mi][ni] = __builtin_amdgcn_mfma_f32_16x16x32_bf16(ah[mi], bl[ni], acc[mi][ni], 0, 0, 0);
                acc[mi][ni] = __builtin_amdgcn_mfma_f32_16x16x32_bf16(al[mi], bh[ni], acc[mi][ni], 0, 0, 0);
            }
        __syncthreads();
    }
    // epilogue: C[row = (lane>>4)*4 + j (+16*mi...)][col = lane&15]
#pragma unroll
    for (int ni = 0; ni < 4; ++ni) {
        int col = n0 + wc * 64 + ni * 16 + l15;
        if (col >= V) continue;
        float bv = bias[col];
#pragma unroll
        for (int mi = 0; mi < 4; ++mi) {
            int rbase = m0 + wr * 64 + mi * 16 + (lane >> 4) * 4;
#pragma unroll
            for (int j = 0; j < 4; ++j) {
                int m = rbase + j;
                int tt = m >> 7, bb = m & 127;
                out[((size_t)bb * S + tt) * V + col] = acc[mi][ni][j] + bv;
            }
        }
    }
}

// ---------------- legacy f32 output projection (fallback path) ----------------
__global__ __launch_bounds__(256) void k_fcn(const float* __restrict__ A,
        const float* __restrict__ Bw, const float* __restrict__ bias,
        float* __restrict__ out, int t_fix) {
    __shared__ float As[16][128];
    __shared__ float Bs[16][128];
    int m0 = blockIdx.x * 128;
    int n0 = blockIdx.y * 128;
    int tid = threadIdx.x;
    int tx = tid & 15, ty = tid >> 4;
    float acc[8][8];
#pragma unroll
    for (int i = 0; i < 8; ++i)
#pragma unroll
        for (int j = 0; j < 8; ++j) acc[i][j] = 0.f;
    int arow = tid >> 1, ak = (tid & 1) * 8;
    int bkk = tid >> 4, bn = (tid & 15) * 8;
    const float4 z4 = make_float4(0.f, 0.f, 0.f, 0.f);
    for (int k0 = 0; k0 < DEC; k0 += 16) {
        {
            const float* ap = A + (size_t)(m0 + arow) * DEC + k0 + ak;
            float4 v0 = *(const float4*)ap;
            float4 v1 = *(const float4*)(ap + 4);
            As[ak + 0][arow] = v0.x; As[ak + 1][arow] = v0.y;
            As[ak + 2][arow] = v0.z; As[ak + 3][arow] = v0.w;
            As[ak + 4][arow] = v1.x; As[ak + 5][arow] = v1.y;
            As[ak + 6][arow] = v1.z; As[ak + 7][arow] = v1.w;
        }
        {
            int n4 = n0 + bn;
            const float* bp = Bw + (size_t)(k0 + bkk) * V + n4;
            float4 v0 = (n4 < V) ? *(const float4*)bp : z4;
            float4 v1 = (n4 + 4 < V) ? *(const float4*)(bp + 4) : z4;
            *(float4*)&Bs[bkk][bn] = v0;
            *(float4*)&Bs[bkk][bn + 4] = v1;
        }
        __syncthreads();
#pragma unroll
        for (int kk = 0; kk < 16; ++kk) {
            float4 a0 = *(const float4*)&As[kk][ty * 8];
            float4 a1 = *(const float4*)&As[kk][ty * 8 + 4];
            float4 b0 = *(const float4*)&Bs[kk][tx * 8];
            float4 b1 = *(const float4*)&Bs[kk][tx * 8 + 4];
            float av[8] = {a0.x, a0.y, a0.z, a0.w, a1.x, a1.y, a1.z, a1.w};
            float bv[8] = {b0.x, b0.y, b0.z, b0.w, b1.x, b1.y, b1.z, b1.w};
#pragma unroll
            for (int i = 0; i < 8; ++i)
#pragma unroll
                for (int j = 0; j < 8; ++j)
                    acc[i][j] = fmaf(av[i], bv[j], acc[i][j]);
        }
        __syncthreads();
    }
#pragma unroll
    for (int i = 0; i < 8; ++i) {
        int mrow = m0 + ty * 8 + i;
        int bb = mrow, tt = t_fix;
        float* op = out + ((size_t)bb * S + tt) * V + n0 + tx * 8;
#pragma unroll
        for (int j = 0; j < 8; ++j) {
            int n = n0 + tx * 8 + j;
            if (n < V) op[j] = acc[i][j] + bias[n];
        }
    }
}

extern "C" void kernel_launch(void* const* d_in, const int* in_sizes, int n_in,
                              void* d_out, int out_size, void* d_ws, size_t ws_size,
                              hipStream_t stream) {
    const float* features = (const float*)d_in[0];
    const int*   captions = (const int*)d_in[1];
    const float* emb      = (const float*)d_in[2];
    const float* Ua_w     = (const float*)d_in[3];
    const float* Ua_b     = (const float*)d_in[4];
    const float* Wa_w     = (const float*)d_in[5];
    const float* Wa_b     = (const float*)d_in[6];
    const float* va_w     = (const float*)d_in[7];
    const float* va_b     = (const float*)d_in[8];
    const float* ih_w     = (const float*)d_in[9];
    const float* ih_b     = (const float*)d_in[10];
    const float* ic_w     = (const float*)d_in[11];
    const float* ic_b     = (const float*)d_in[12];
    const float* W_ih     = (const float*)d_in[13];
    const float* b_ih     = (const float*)d_in[14];
    const float* W_hh     = (const float*)d_in[15];
    const float* b_hh     = (const float*)d_in[16];
    const float* fcn_w    = (const float*)d_in[17];
    const float* fcn_b    = (const float*)d_in[18];
    float* out = (float*)d_out;
    char* wsb  = (char*)d_ws;

    size_t off = 0;
    __hip_bfloat16* Uf    = (__hip_bfloat16*)(wsb + off); off += (size_t)B * P * ATT * 2;    // 12.8MB
    __hip_bfloat16* featT = (__hip_bfloat16*)(wsb + off); off += (size_t)B * ENC * PP * 2;   // 26.2MB
    __hip_bfloat16* WaT   = (__hip_bfloat16*)(wsb + off); off += (size_t)ATT * DEC * 2;
    float* partials = (float*)(wsb + off); off += (size_t)KS * B * NG * 4;                   // 16.8MB
    float* hbuf     = (float*)(wsb + off); off += (size_t)B * DEC * 4;
    float* cbufA    = (float*)(wsb + off); off += (size_t)B * DEC * 4;
    float* cbufB    = (float*)(wsb + off); off += (size_t)B * DEC * 4;
    float* ctxp     = (float*)(wsb + off); off += (size_t)2 * B * ENC * 4;
    float* mlp      = (float*)(wsb + off); off += 4096;
    float* meanf    = ctxp;   // alias: meanf used only before ctxp's first use
    size_t need_min = off;
    __hip_bfloat16* HallH = (__hip_bfloat16*)(wsb + off); off += (size_t)S * B * DEC * 2;    // 33.5MB
    __hip_bfloat16* HallL = (__hip_bfloat16*)(wsb + off); off += (size_t)S * B * DEC * 2;    // 33.5MB
    size_t need_hall = off;
    __hip_bfloat16* Gemb = (__hip_bfloat16*)(wsb + off);
    off += (size_t)S * B * NG * 2;                                                           // 134MB
    size_t need_gemb = off;
    // WhiT/WloT alias the (dead after the loop) Uf region: 2*5120*512*2 = 10.5MB <= 12.8MB
    __hip_bfloat16* WhiT = (__hip_bfloat16*)Uf;
    __hip_bfloat16* WloT = WhiT + (size_t)NP * 512;

    (void)need_min;
    int use_hall = ws_size >= need_hall;
    int use_gemb = ws_size >= need_gemb;

    k_mean<<<256, 256, 0, stream>>>(features, meanf);
    k_init_hc<<<256, 256, 0, stream>>>(meanf, ih_w, ih_b, ic_w, ic_b, hbuf, cbufA);
    k_uf<<<3136, 256, 0, stream>>>(features, Ua_w, Ua_b, Uf);
    k_featT<<<dim3(128, 25), 512, 0, stream>>>(features, featT);
    k_watr<<<512, 256, 0, stream>>>(Wa_w, WaT);
    if (use_gemb)
        k_gemb<<<dim3(256, 16), 256, 0, stream>>>(emb, captions, W_ih, Gemb);

    for (int t = 0; t <= S; ++t) {
        const float* crd = (t & 1) ? cbufA : cbufB;
        float*       cwr = (t & 1) ? cbufB : cbufA;
        k_attn_cell<<<256, 1024, 0, stream>>>(partials, Gemb, b_ih, b_hh,
                hbuf, crd, cwr, HallH, HallL, WaT, Wa_b, Uf, featT, va_w, va_b,
                ctxp, mlp, t, use_gemb, use_hall);
        if (t < S)
            k_gates<<<dim3(32, KS), 256, 0, stream>>>(emb, captions, t, ctxp, mlp,
                    hbuf, W_ih, W_hh, partials, use_gemb);
        if (!use_hall && t > 0)
            k_fcn<<<dim3(1, 40), 256, 0, stream>>>(hbuf, fcn_w, fcn_b, out, t - 1);
    }
    if (use_hall) {
        k_wsplit<<<dim3(16, 80), 256, 0, stream>>>(fcn_w, WhiT, WloT);
        k_fcn_mfma<<<dim3(256, 40), 256, 0, stream>>>(HallH, HallL, WhiT, WloT, fcn_b, out);
    }
}